// Round 4
// baseline (6388.092 us; speedup 1.0000x reference)
//
#include <hip/hip_runtime.h>

// DeepLSTM on MI355X — persistent kernel (plain launch, co-resident), weights in VGPR/AGPR.
// ROUND 6: K-loop software pipeline, depth-4 register relay, raw s_barrier per chunk.
// ROUND 7 (REVERTED): per-step agent acquire fence — 2x regression (L2-wide writeback).
// ROUND 8: h relay loads = inline-asm global_load_dwordx4 sc1 (coalescable, MALL-coherent)
//   + manual vmcnt pipeline waits. 5244 -> 3825 us.
// ROUND 9: centralized two-phase grid barrier (master sweeps arrivals, single release
//   line polled by one lane per block). 3825 -> 2831 us.
// ROUND 10: halve redundant h-read MALL traffic (42 -> 21 MB/step): 512-thread blocks,
//   rows-per-block doubled. L1 = 32 blk x 128 gate rows, L2 = 64 blk x 64 rows,
//   head = 8 blk x 32 cols. Grid 208 -> 104. Per-wave inner structure unchanged.

typedef __attribute__((ext_vector_type(8))) short short8;
typedef __attribute__((ext_vector_type(16))) float f32x16;
typedef __attribute__((ext_vector_type(4))) float f32x4;

#define Tn 256
#define In 256
#define Hn 1024
#define On 256
#define SP 136            // LDS act row stride (elems): 272B rows, 16B-aligned
#define NL1 32
#define NL2 64
#define NY  8
#define NBLK (NL1 + NL2 + NY)   // 104
#define BDIM 512
#define CHUNK_B 17408     // 64*SP*2 bytes per LDS act chunk (128 K-cols)
#define SG_B 33792        // gate xchg: L1 64*132*4, L2 2*64*66*4 (same size)
#define SMEM_SZ (2*CHUNK_B + SG_B + 8192)   // 76800 (L1 needs 8KB cell state)
#define BHe 65536
#define RELEASE_IDX 240   // release flag: own 64B line (arrival flags occupy idx 0..103)

// d_ws layout
#define WS_WIH1 0
#define WS_WHH1 2097152
#define WS_WIH2 10485760
#define WS_WHH2 20971520
#define WS_WL   29360128
#define WS_X    30015488
#define WS_H1   38404096
#define WS_H2   38666240
#define WS_ARR  38928384

// s_waitcnt lgkmcnt(0), vmcnt/expcnt unconstrained (gfx9 encoding)
#define WAIT_LGKM0() __builtin_amdgcn_s_waitcnt(0xC07F)
#define RAW_BARRIER() do { \
    WAIT_LGKM0(); \
    __builtin_amdgcn_sched_barrier(0); \
    __builtin_amdgcn_s_barrier(); \
    __builtin_amdgcn_sched_barrier(0); \
  } while (0)

// Wait for relay loads: 2 loads/chunk, allow `rem` future chunks in flight.
#define STAGE_WAIT(rem) do { \
    __builtin_amdgcn_sched_barrier(0); \
    if ((rem) >= 3)      asm volatile("s_waitcnt vmcnt(6)" ::: "memory"); \
    else if ((rem) == 2) asm volatile("s_waitcnt vmcnt(4)" ::: "memory"); \
    else if ((rem) == 1) asm volatile("s_waitcnt vmcnt(2)" ::: "memory"); \
    else                 asm volatile("s_waitcnt vmcnt(0)" ::: "memory"); \
    __builtin_amdgcn_sched_barrier(0); \
  } while (0)

// Plain cached 16B load (x: immutable, L1/L2-cacheable)
#define GLD16(dst, ptr) \
  asm volatile("global_load_dwordx4 %0, %1, off" : "=v"(dst) : "v"(ptr))
// Agent-coherent 16B load (h: bypass L1/L2 via sc1, read from coherence point;
// same visibility as an agent-scope relaxed atomic load, but TA-coalescable)
#define GLD16C(dst, ptr) \
  asm volatile("global_load_dwordx4 %0, %1, off sc1" : "=v"(dst) : "v"(ptr))

static __device__ __forceinline__ unsigned short f2b(float f) {
  union { float f; unsigned int i; } v; v.f = f;
  unsigned int u = v.i;
  return (unsigned short)((u + 0x7FFFu + ((u >> 16) & 1u)) >> 16);  // RNE
}
static __device__ __forceinline__ float sigm(float x) { return 1.0f / (1.0f + __expf(-x)); }
static __device__ __forceinline__ float tanhf_(float x) {
  float ax = fabsf(x);
  float e = __expf(-2.0f * ax);
  return copysignf((1.0f - e) / (1.0f + e), x);
}
static __device__ __forceinline__ int ld32a(const void* p) {
  return __hip_atomic_load((const int*)p, __ATOMIC_RELAXED, __HIP_MEMORY_SCOPE_AGENT);
}
static __device__ __forceinline__ void st32a(void* p, unsigned int v) {
  __hip_atomic_store((unsigned int*)p, v, __ATOMIC_RELAXED, __HIP_MEMORY_SCOPE_AGENT);
}
static __device__ __forceinline__ void st64a(void* p, unsigned long long v) {
  __hip_atomic_store((unsigned long long*)p, v, __ATOMIC_RELAXED, __HIP_MEMORY_SCOPE_AGENT);
}

static __device__ __forceinline__ void grid_barrier(int* arrive, int bid, int tid,
                                                    int lane, int tgt) {
  __syncthreads();   // full drain (vmcnt0): h-stores visible before publish
  if (tid == 0)
    st32a(&arrive[bid], (unsigned int)tgt);
  if (bid == 0) {
    // master: wave 0 sweeps all arrival flags, then publishes release
    if (tid < 64) {
      bool done = false;
      while (!done) {
        bool ok = true;
        #pragma unroll
        for (int j = 0; j < 2; ++j) {
          int idx = lane + j * 64;
          if (idx < NBLK) {
            int v = ld32a(&arrive[idx]);
            ok = ok && (v >= tgt);
          }
        }
        done = __all(ok);
        if (!done) __builtin_amdgcn_s_sleep(1);
      }
      if (tid == 0)
        st32a(&arrive[RELEASE_IDX], (unsigned int)tgt);
    }
    __syncthreads();
  } else {
    // followers: one lane polls the single release line
    if (tid == 0) {
      while (ld32a(&arrive[RELEASE_IDX]) < tgt) __builtin_amdgcn_s_sleep(1);
    }
    __syncthreads();
  }
}

__global__ void __launch_bounds__(256) cvt_bf16(const float* __restrict__ src,
                                                unsigned short* __restrict__ dst, int n4) {
  int i = blockIdx.x * blockDim.x + threadIdx.x;
  if (i >= n4) return;
  float4 v = ((const float4*)src)[i];
  ushort4 o;
  o.x = f2b(v.x); o.y = f2b(v.y); o.z = f2b(v.z); o.w = f2b(v.w);
  ((ushort4*)dst)[i] = o;
}

__global__ void __launch_bounds__(256) prep_zero(unsigned short* h1buf,
                                                 unsigned short* h2buf,
                                                 int* arrive) {
  int i = blockIdx.x * blockDim.x + threadIdx.x;
  st64a((unsigned long long*)h1buf + i, 0ull);
  st64a((unsigned long long*)h1buf + 16384 + i, 0ull);
  st64a((unsigned long long*)h2buf + i, 0ull);
  st64a((unsigned long long*)h2buf + 16384 + i, 0ull);
  if (i < 256) st32a(arrive + i, 0u);
}

__global__ void __launch_bounds__(512, 1) lstm_persist(
    const unsigned short* __restrict__ x,
    const unsigned short* __restrict__ Wih1, const unsigned short* __restrict__ Whh1,
    const float* __restrict__ bih1, const float* __restrict__ bhh1,
    const unsigned short* __restrict__ Wih2, const unsigned short* __restrict__ Whh2,
    const float* __restrict__ bih2, const float* __restrict__ bhh2,
    const unsigned short* __restrict__ Wl,  const float* __restrict__ bl,
    float* __restrict__ out,
    unsigned short* __restrict__ h1buf, unsigned short* __restrict__ h2buf,
    int* __restrict__ arrive)
{
  extern __shared__ char smem[];
  unsigned short* sbuf0 = (unsigned short*)smem;
  unsigned short* sbuf1 = (unsigned short*)(smem + CHUNK_B);
  float* sG = (float*)(smem + 2 * CHUNK_B);
  float* sc = (float*)(smem + 2 * CHUNK_B + SG_B);

  const int tid = threadIdx.x;
  const int bid = blockIdx.x;
  const int lane = tid & 63;
  const int wid = tid >> 6;           // 0..7
  const int srow = tid >> 3;          // staging row 0..63
  const int sseg = tid & 7;           // 32B segment within row

  for (int e = tid; e < 2048; e += BDIM) sc[e] = 0.0f;

  uint4 rs[4][2];                     // depth-4 relay: 32B/thread/chunk

  if (bid < NL1) {
    // =================== layer 1: 32 blocks x 128 gate rows (32 h-cols) ===========
    const int j0 = bid << 5;
    const int mtile = wid & 1, ntile = wid >> 1;   // ntile 0..3
    const int arow = mtile * 32 + (lane & 31);
    const int brow = ntile * 32 + (lane & 31);     // 0..127
    const int gr = ((brow >> 5) << 10) + j0 + (brow & 31);
    const int hi8 = (lane >> 5) << 3;

    short8 w[80];
    #pragma unroll
    for (int c = 0; c < 10; ++c) {
      const unsigned short* wrow = (c < 2) ? (Wih1 + (size_t)gr * In + c * 128)
                                           : (Whh1 + (size_t)gr * Hn + (c - 2) * 128);
      #pragma unroll
      for (int k8 = 0; k8 < 8; ++k8)
        w[c * 8 + k8] = *(const short8*)(wrow + k8 * 16 + hi8);
    }
    float bs[2][2][4];
    #pragma unroll
    for (int p = 0; p < 2; ++p) {
      int pi = tid + p * BDIM, op = (pi & 15) << 1;
      #pragma unroll
      for (int k = 0; k < 2; ++k) {
        int o = op + k;
        #pragma unroll
        for (int g = 0; g < 4; ++g)
          bs[p][k][g] = bih1[g * 1024 + j0 + o] + bhh1[g * 1024 + j0 + o];
      }
    }

    for (int s = 0; s < Tn; ++s) {
      const int t = s;
      const unsigned short* h1rd = h1buf + ((t + 1) & 1) * BHe;
      unsigned short* h1wr = h1buf + (t & 1) * BHe;
      f32x16 acc0 = {}, acc1 = {};

      auto ldc = [&](int cc, int d) {
        if (cc < 2) {
          const char* p = (const char*)(x + ((size_t)srow * Tn + t) * In + cc * 128 + sseg * 16);
          GLD16(rs[d][0], p); GLD16(rs[d][1], p + 16);
        } else {
          const char* p = (const char*)(h1rd + (size_t)srow * Hn + (cc - 2) * 128 + sseg * 16);
          GLD16C(rs[d][0], p); GLD16C(rs[d][1], p + 16);
        }
      };
      ldc(0, 0); ldc(1, 1); ldc(2, 2); ldc(3, 3);

      #pragma unroll
      for (int c = 0; c < 10; ++c) {
        unsigned short* buf = (c & 1) ? sbuf1 : sbuf0;
        STAGE_WAIT(9 - c);
        {
          uint4* d4 = (uint4*)(buf + srow * SP + sseg * 16);
          d4[0] = rs[c & 3][0]; d4[1] = rs[c & 3][1];
        }
        if (c + 4 < 10) ldc(c + 4, c & 3);
        RAW_BARRIER();
        const unsigned short* ab = buf + arow * SP + hi8;
        #pragma unroll
        for (int k8 = 0; k8 < 8; k8 += 2) {
          acc0 = __builtin_amdgcn_mfma_f32_32x32x16_bf16(*(const short8*)(ab + k8 * 16),      w[c * 8 + k8],     acc0, 0, 0, 0);
          acc1 = __builtin_amdgcn_mfma_f32_32x32x16_bf16(*(const short8*)(ab + k8 * 16 + 16), w[c * 8 + k8 + 1], acc1, 0, 0, 0);
        }
      }
      RAW_BARRIER();

      f32x16 accv = acc0 + acc1;
      #pragma unroll
      for (int i = 0; i < 16; ++i) {  // C/D: col=lane&31, row=(reg&3)+8*(reg>>2)+4*(lane>>5)
        int rm = (i & 3) + ((i >> 2) << 3) + ((lane >> 5) << 2);
        sG[(mtile * 32 + rm) * 132 + brow] = accv[i];
      }
      __syncthreads();

      #pragma unroll
      for (int p = 0; p < 2; ++p) {
        int pi = tid + p * BDIM;
        int b = pi >> 4, op = (pi & 15) << 1;
        const float* gb = sG + b * 132;
        unsigned int pack = 0;
        #pragma unroll
        for (int k = 0; k < 2; ++k) {
          int o = op + k, e = b * 32 + o;
          float ig = gb[o]      + bs[p][k][0];
          float fg = gb[32 + o] + bs[p][k][1];
          float gg = gb[64 + o] + bs[p][k][2];
          float og = gb[96 + o] + bs[p][k][3];
          float cn = sigm(fg) * sc[e] + sigm(ig) * tanhf_(gg);
          sc[e] = cn;
          pack |= ((unsigned int)f2b(sigm(og) * tanhf_(cn))) << (16 * k);
        }
        st32a(h1wr + b * Hn + j0 + op, pack);
      }
      grid_barrier(arrive, bid, tid, lane, s + 1);
    }
    grid_barrier(arrive, bid, tid, lane, Tn + 1);

  } else if (bid < NL1 + NL2) {
    // =================== layer 2: 64 blocks x 64 gate rows (16 h-cols) ============
    const int j0 = (bid - NL1) << 4;
    const int mtile = wid & 1, ntile = (wid >> 1) & 1, ks = wid >> 2;
    const int arow = mtile * 32 + (lane & 31);
    const int brow = ntile * 32 + (lane & 31);     // 0..63
    const int gr = ((brow >> 4) << 10) + j0 + (brow & 15);
    const int hi8 = (lane >> 5) << 3;

    short8 w[80];
    if (ks == 0) {
      #pragma unroll
      for (int c = 0; c < 10; ++c)
        #pragma unroll
        for (int k8 = 0; k8 < 8; ++k8)
          w[c * 8 + k8] = *(const short8*)(Wih2 + (size_t)gr * 1280 + c * 128 + k8 * 16 + hi8);
    } else {
      #pragma unroll
      for (int c = 0; c < 8; ++c)
        #pragma unroll
        for (int k8 = 0; k8 < 8; ++k8)
          w[c * 8 + k8] = *(const short8*)(Whh2 + (size_t)gr * Hn + c * 128 + k8 * 16 + hi8);
    }
    float bs[2][4];
    {
      int op = (tid & 7) << 1;
      #pragma unroll
      for (int k = 0; k < 2; ++k) {
        int o = op + k;
        #pragma unroll
        for (int g = 0; g < 4; ++g)
          bs[k][g] = bih2[g * 1024 + j0 + o] + bhh2[g * 1024 + j0 + o];
      }
    }

    grid_barrier(arrive, bid, tid, lane, 1);

    for (int s = 1; s <= Tn; ++s) {
      const int t = s - 1;
      const unsigned short* h1rd = h1buf + (t & 1) * BHe;        // h1(t)
      const unsigned short* h2rd = h2buf + ((t + 1) & 1) * BHe;  // h2(t-1)
      unsigned short* h2wr = h2buf + (t & 1) * BHe;              // h2(t)
      f32x16 acc0 = {}, acc1 = {};

      auto ldc = [&](int cc, int d) {
        if (cc < 2) {
          const char* p = (const char*)(x + ((size_t)srow * Tn + t) * In + cc * 128 + sseg * 16);
          GLD16(rs[d][0], p); GLD16(rs[d][1], p + 16);
        } else {
          const unsigned short* src = (cc < 10) ? (h1rd + (size_t)srow * Hn + (cc - 2) * 128)
                                                : (h2rd + (size_t)srow * Hn + (cc - 10) * 128);
          const char* p = (const char*)(src + sseg * 16);
          GLD16C(rs[d][0], p); GLD16C(rs[d][1], p + 16);
        }
      };
      ldc(0, 0); ldc(1, 1); ldc(2, 2); ldc(3, 3);

      #pragma unroll
      for (int c = 0; c < 18; ++c) {
        unsigned short* buf = (c & 1) ? sbuf1 : sbuf0;
        STAGE_WAIT(17 - c);
        {
          uint4* d4 = (uint4*)(buf + srow * SP + sseg * 16);
          d4[0] = rs[c & 3][0]; d4[1] = rs[c & 3][1];
        }
        if (c + 4 < 18) ldc(c + 4, c & 3);
        RAW_BARRIER();
        bool active = (ks == 0) ? (c < 10) : (c >= 10);
        if (active) {
          int ib = ((ks == 0) ? c : (c - 10)) * 8;
          const unsigned short* ab = buf + arow * SP + hi8;
          #pragma unroll
          for (int k8 = 0; k8 < 8; k8 += 2) {
            acc0 = __builtin_amdgcn_mfma_f32_32x32x16_bf16(*(const short8*)(ab + k8 * 16),      w[ib + k8],     acc0, 0, 0, 0);
            acc1 = __builtin_amdgcn_mfma_f32_32x32x16_bf16(*(const short8*)(ab + k8 * 16 + 16), w[ib + k8 + 1], acc1, 0, 0, 0);
          }
        }
      }
      RAW_BARRIER();

      f32x16 accv = acc0 + acc1;
      #pragma unroll
      for (int i = 0; i < 16; ++i) {
        int rm = (i & 3) + ((i >> 2) << 3) + ((lane >> 5) << 2);
        sG[ks * 4224 + (mtile * 32 + rm) * 66 + brow] = accv[i];
      }
      __syncthreads();

      {
        int b = tid >> 3, op = (tid & 7) << 1;
        const float* g0 = sG + b * 66;
        const float* g1 = sG + 4224 + b * 66;
        unsigned int pack = 0;
        #pragma unroll
        for (int k = 0; k < 2; ++k) {
          int o = op + k, e = b * 16 + o;
          float ig = g0[o]      + g1[o]      + bs[k][0];
          float fg = g0[16 + o] + g1[16 + o] + bs[k][1];
          float gg = g0[32 + o] + g1[32 + o] + bs[k][2];
          float og = g0[48 + o] + g1[48 + o] + bs[k][3];
          float cn = sigm(fg) * sc[e] + sigm(ig) * tanhf_(gg);
          sc[e] = cn;
          pack |= ((unsigned int)f2b(sigm(og) * tanhf_(cn))) << (16 * k);
        }
        st32a(h2wr + b * Hn + j0 + op, pack);
      }
      grid_barrier(arrive, bid, tid, lane, s + 1);
    }

  } else {
    // =================== head: 8 blocks x 32 out-cols =============================
    const int o0 = (bid - NL1 - NL2) << 5;
    const int coltile = wid & 1, rowtile = wid >> 1;   // rowtile 0..3
    const int quad = lane >> 4;
    const int l15 = lane & 15;
    const int hi8y = quad << 3;

    short8 wy[40];
    #pragma unroll
    for (int c = 0; c < 10; ++c)
      #pragma unroll
      for (int q = 0; q < 4; ++q)
        wy[c * 4 + q] = *(const short8*)(Wl + (size_t)(o0 + coltile * 16 + l15) * 1280 + c * 128 + q * 32 + hi8y);
    const float blv = bl[o0 + coltile * 16 + l15];

    grid_barrier(arrive, bid, tid, lane, 1);
    grid_barrier(arrive, bid, tid, lane, 2);

    for (int s = 2; s <= Tn + 1; ++s) {
      const int t = s - 2;
      const unsigned short* h2rd = h2buf + (t & 1) * BHe;   // h2(t)
      f32x4 acc0 = {}, acc1 = {};

      auto ldc = [&](int cc, int d) {
        if (cc < 2) {
          const char* p = (const char*)(x + ((size_t)srow * Tn + t) * In + cc * 128 + sseg * 16);
          GLD16(rs[d][0], p); GLD16(rs[d][1], p + 16);
        } else {
          const char* p = (const char*)(h2rd + (size_t)srow * Hn + (cc - 2) * 128 + sseg * 16);
          GLD16C(rs[d][0], p); GLD16C(rs[d][1], p + 16);
        }
      };
      ldc(0, 0); ldc(1, 1); ldc(2, 2); ldc(3, 3);

      #pragma unroll
      for (int c = 0; c < 10; ++c) {
        unsigned short* buf = (c & 1) ? sbuf1 : sbuf0;
        STAGE_WAIT(9 - c);
        {
          uint4* d4 = (uint4*)(buf + srow * SP + sseg * 16);
          d4[0] = rs[c & 3][0]; d4[1] = rs[c & 3][1];
        }
        if (c + 4 < 10) ldc(c + 4, c & 3);
        RAW_BARRIER();
        const unsigned short* ab = buf + (rowtile * 16 + l15) * SP + hi8y;
        acc0 = __builtin_amdgcn_mfma_f32_16x16x32_bf16(*(const short8*)(ab),      wy[c * 4 + 0], acc0, 0, 0, 0);
        acc1 = __builtin_amdgcn_mfma_f32_16x16x32_bf16(*(const short8*)(ab + 32), wy[c * 4 + 1], acc1, 0, 0, 0);
        acc0 = __builtin_amdgcn_mfma_f32_16x16x32_bf16(*(const short8*)(ab + 64), wy[c * 4 + 2], acc0, 0, 0, 0);
        acc1 = __builtin_amdgcn_mfma_f32_16x16x32_bf16(*(const short8*)(ab + 96), wy[c * 4 + 3], acc1, 0, 0, 0);
      }
      RAW_BARRIER();

      f32x4 accv = acc0 + acc1;
      #pragma unroll
      for (int i = 0; i < 4; ++i) {   // C/D 16x16: col=lane&15, row=(lane>>4)*4+reg
        int b = rowtile * 16 + quad * 4 + i;
        out[((size_t)b * Tn + t) * On + o0 + coltile * 16 + l15] = accv[i] + blv;
      }
      if (s <= Tn) grid_barrier(arrive, bid, tid, lane, s + 1);
    }
  }
}

extern "C" void kernel_launch(void* const* d_in, const int* in_sizes, int n_in,
                              void* d_out, int out_size, void* d_ws, size_t ws_size,
                              hipStream_t stream) {
  (void)in_sizes; (void)n_in; (void)out_size; (void)ws_size;
  const float* xf    = (const float*)d_in[0];
  const float* Wih1f = (const float*)d_in[1];
  const float* Whh1f = (const float*)d_in[2];
  const float* bih1  = (const float*)d_in[3];
  const float* bhh1  = (const float*)d_in[4];
  const float* Wih2f = (const float*)d_in[5];
  const float* Whh2f = (const float*)d_in[6];
  const float* bih2  = (const float*)d_in[7];
  const float* bhh2  = (const float*)d_in[8];
  const float* Wlf   = (const float*)d_in[9];
  const float* bl    = (const float*)d_in[10];
  float* out = (float*)d_out;

  char* ws = (char*)d_ws;
  unsigned short* Wih1b = (unsigned short*)(ws + WS_WIH1);
  unsigned short* Whh1b = (unsigned short*)(ws + WS_WHH1);
  unsigned short* Wih2b = (unsigned short*)(ws + WS_WIH2);
  unsigned short* Whh2b = (unsigned short*)(ws + WS_WHH2);
  unsigned short* Wlb   = (unsigned short*)(ws + WS_WL);
  unsigned short* xb    = (unsigned short*)(ws + WS_X);
  unsigned short* h1buf = (unsigned short*)(ws + WS_H1);
  unsigned short* h2buf = (unsigned short*)(ws + WS_H2);
  int* arrive           = (int*)(ws + WS_ARR);

  static int attr_done = 0;
  if (!attr_done) {
    hipFuncSetAttribute((const void*)lstm_persist,
                        hipFuncAttributeMaxDynamicSharedMemorySize, SMEM_SZ);
    attr_done = 1;
  }

  hipLaunchKernelGGL(cvt_bf16, dim3(1024), dim3(256), 0, stream, Wih1f, Wih1b, 262144);
  hipLaunchKernelGGL(cvt_bf16, dim3(4096), dim3(256), 0, stream, Whh1f, Whh1b, 1048576);
  hipLaunchKernelGGL(cvt_bf16, dim3(5120), dim3(256), 0, stream, Wih2f, Wih2b, 1310720);
  hipLaunchKernelGGL(cvt_bf16, dim3(4096), dim3(256), 0, stream, Whh2f, Whh2b, 1048576);
  hipLaunchKernelGGL(cvt_bf16, dim3(320),  dim3(256), 0, stream, Wlf,   Wlb,   81920);
  hipLaunchKernelGGL(cvt_bf16, dim3(4096), dim3(256), 0, stream, xf,    xb,    1048576);

  hipLaunchKernelGGL(prep_zero, dim3(64), dim3(256), 0, stream, h1buf, h2buf, arrive);

  hipLaunchKernelGGL(lstm_persist, dim3(NBLK), dim3(BDIM), SMEM_SZ, stream,
                     xb, Wih1b, Whh1b, bih1, bhh1, Wih2b, Whh2b, bih2, bhh2, Wlb, bl,
                     out, h1buf, h2buf, arrive);
}

// Round 5
// 2348.644 us; speedup vs baseline: 2.7199x; 2.7199x over previous
//
#include <hip/hip_runtime.h>

// DeepLSTM on MI355X — persistent kernel (plain launch, 208 blocks, co-resident),
// weights persistent in VGPR/AGPR (requires 256-thr blocks = 1 wave/SIMD; R10's 512-thr
// geometry spilled w[80] -> FETCH x3.5, reverted).
// ROUND 8: h relay loads = inline-asm global_load_dwordx4 sc1 + manual vmcnt pipeline.
// ROUND 9: centralized two-phase grid barrier. 3825 -> 2831 us.
// ROUND 11: relay address map re-coalesced. Old map put one 16B lane per 64B segment
//   (64 MALL requests/instr, 2.75M req/step chip-wide = request-rate wall, invisible in
//   FETCH/WRITE which count HBM only). New map: thread tid covers row tid>>4 + 16j,
//   16B-slot tid&15 -> per instr 4 rows x 256B contiguous = 8 line requests (8x fewer).
//   LDS contents byte-identical to R3; MFMA side untouched.

typedef __attribute__((ext_vector_type(8))) short short8;
typedef __attribute__((ext_vector_type(16))) float f32x16;
typedef __attribute__((ext_vector_type(4))) float f32x4;

#define Tn 256
#define In 256
#define Hn 1024
#define On 256
#define SP 136            // LDS act row stride (elems): 272B rows, 16B-aligned
#define NL1 64
#define NL2 128
#define NY  16
#define NBLK (NL1 + NL2 + NY)   // 208
#define CHUNK_B 17408     // 64*SP*2 bytes per LDS act chunk (128 K-cols)
#define SMEM_SZ 55808     // 2*CHUNK_B + 16896 (gate xchg) + 4096 (cell state)
#define BHe 65536
#define RELEASE_IDX 240   // release flag: own 64B line (arrival flags occupy idx 0..207)

// d_ws layout
#define WS_WIH1 0
#define WS_WHH1 2097152
#define WS_WIH2 10485760
#define WS_WHH2 20971520
#define WS_WL   29360128
#define WS_X    30015488
#define WS_H1   38404096
#define WS_H2   38666240
#define WS_ARR  38928384

// s_waitcnt lgkmcnt(0), vmcnt/expcnt unconstrained (gfx9 encoding)
#define WAIT_LGKM0() __builtin_amdgcn_s_waitcnt(0xC07F)
#define RAW_BARRIER() do { \
    WAIT_LGKM0(); \
    __builtin_amdgcn_sched_barrier(0); \
    __builtin_amdgcn_s_barrier(); \
    __builtin_amdgcn_sched_barrier(0); \
  } while (0)

// Wait for relay loads: allow `rem` chunks (4 dwordx4 each) to stay in flight.
#define STAGE_WAIT(rem) do { \
    __builtin_amdgcn_sched_barrier(0); \
    if ((rem) >= 3)      asm volatile("s_waitcnt vmcnt(12)" ::: "memory"); \
    else if ((rem) == 2) asm volatile("s_waitcnt vmcnt(8)"  ::: "memory"); \
    else if ((rem) == 1) asm volatile("s_waitcnt vmcnt(4)"  ::: "memory"); \
    else                 asm volatile("s_waitcnt vmcnt(0)"  ::: "memory"); \
    __builtin_amdgcn_sched_barrier(0); \
  } while (0)

// Plain cached 16B load (x: immutable, L1/L2-cacheable)
#define GLD16(dst, ptr) \
  asm volatile("global_load_dwordx4 %0, %1, off" : "=v"(dst) : "v"(ptr))
// Agent-coherent 16B load (h: sc1 -> coherence point, TA-coalescable)
#define GLD16C(dst, ptr) \
  asm volatile("global_load_dwordx4 %0, %1, off sc1" : "=v"(dst) : "v"(ptr))

static __device__ __forceinline__ unsigned short f2b(float f) {
  union { float f; unsigned int i; } v; v.f = f;
  unsigned int u = v.i;
  return (unsigned short)((u + 0x7FFFu + ((u >> 16) & 1u)) >> 16);  // RNE
}
static __device__ __forceinline__ float sigm(float x) { return 1.0f / (1.0f + __expf(-x)); }
static __device__ __forceinline__ float tanhf_(float x) {
  float ax = fabsf(x);
  float e = __expf(-2.0f * ax);
  return copysignf((1.0f - e) / (1.0f + e), x);
}
static __device__ __forceinline__ int ld32a(const void* p) {
  return __hip_atomic_load((const int*)p, __ATOMIC_RELAXED, __HIP_MEMORY_SCOPE_AGENT);
}
static __device__ __forceinline__ void st32a(void* p, unsigned int v) {
  __hip_atomic_store((unsigned int*)p, v, __ATOMIC_RELAXED, __HIP_MEMORY_SCOPE_AGENT);
}
static __device__ __forceinline__ void st64a(void* p, unsigned long long v) {
  __hip_atomic_store((unsigned long long*)p, v, __ATOMIC_RELAXED, __HIP_MEMORY_SCOPE_AGENT);
}

static __device__ __forceinline__ void grid_barrier(int* arrive, int bid, int tid,
                                                    int lane, int tgt) {
  __syncthreads();   // full drain (vmcnt0): h-stores visible before publish
  if (tid == 0)
    st32a(&arrive[bid], (unsigned int)tgt);
  if (bid == 0) {
    // master: wave 0 sweeps all arrival flags, then publishes release
    if (tid < 64) {
      bool done = false;
      while (!done) {
        bool ok = true;
        #pragma unroll
        for (int j = 0; j < 4; ++j) {
          int idx = lane + j * 64;
          if (idx < NBLK) {
            int v = ld32a(&arrive[idx]);
            ok = ok && (v >= tgt);
          }
        }
        done = __all(ok);
        if (!done) __builtin_amdgcn_s_sleep(1);
      }
      if (tid == 0)
        st32a(&arrive[RELEASE_IDX], (unsigned int)tgt);
    }
    __syncthreads();
  } else {
    // followers: one lane polls the single release line
    if (tid == 0) {
      while (ld32a(&arrive[RELEASE_IDX]) < tgt) __builtin_amdgcn_s_sleep(1);
    }
    __syncthreads();
  }
}

__global__ void __launch_bounds__(256) cvt_bf16(const float* __restrict__ src,
                                                unsigned short* __restrict__ dst, int n4) {
  int i = blockIdx.x * blockDim.x + threadIdx.x;
  if (i >= n4) return;
  float4 v = ((const float4*)src)[i];
  ushort4 o;
  o.x = f2b(v.x); o.y = f2b(v.y); o.z = f2b(v.z); o.w = f2b(v.w);
  ((ushort4*)dst)[i] = o;
}

__global__ void __launch_bounds__(256) prep_zero(unsigned short* h1buf,
                                                 unsigned short* h2buf,
                                                 int* arrive) {
  int i = blockIdx.x * blockDim.x + threadIdx.x;
  st64a((unsigned long long*)h1buf + i, 0ull);
  st64a((unsigned long long*)h1buf + 16384 + i, 0ull);
  st64a((unsigned long long*)h2buf + i, 0ull);
  st64a((unsigned long long*)h2buf + 16384 + i, 0ull);
  if (i < 256) st32a(arrive + i, 0u);
}

__global__ void __launch_bounds__(256, 1) lstm_persist(
    const unsigned short* __restrict__ x,
    const unsigned short* __restrict__ Wih1, const unsigned short* __restrict__ Whh1,
    const float* __restrict__ bih1, const float* __restrict__ bhh1,
    const unsigned short* __restrict__ Wih2, const unsigned short* __restrict__ Whh2,
    const float* __restrict__ bih2, const float* __restrict__ bhh2,
    const unsigned short* __restrict__ Wl,  const float* __restrict__ bl,
    float* __restrict__ out,
    unsigned short* __restrict__ h1buf, unsigned short* __restrict__ h2buf,
    int* __restrict__ arrive)
{
  extern __shared__ char smem[];
  unsigned short* sbuf0 = (unsigned short*)smem;
  unsigned short* sbuf1 = (unsigned short*)(smem + CHUNK_B);
  float* sG = (float*)(smem + 2 * CHUNK_B);
  float* sc = (float*)(smem + 2 * CHUNK_B + 16896);

  const int tid = threadIdx.x;
  const int bid = blockIdx.x;
  const int lane = tid & 63;
  const int wid = tid >> 6;
  const int r0  = tid >> 4;           // base staging row 0..15 (rows r0+16j)
  const int sg  = tid & 15;           // 16B column slot within 256B row-chunk

  for (int e = tid; e < 1024; e += 256) sc[e] = 0.0f;

  uint4 rs[4][4];                     // depth-4 relay: 64B/thread/chunk

  if (bid < NL1) {
    // =================== layer 1 ===================
    const int j0 = bid << 4;
    const int mtile = wid & 1, ntile = wid >> 1;
    const int arow = mtile * 32 + (lane & 31);
    const int brow = ntile * 32 + (lane & 31);
    const int gr = ((brow >> 4) << 10) + j0 + (brow & 15);
    const int hi8 = (lane >> 5) << 3;

    short8 w[80];
    #pragma unroll
    for (int c = 0; c < 10; ++c) {
      const unsigned short* wrow = (c < 2) ? (Wih1 + (size_t)gr * In + c * 128)
                                           : (Whh1 + (size_t)gr * Hn + (c - 2) * 128);
      #pragma unroll
      for (int k8 = 0; k8 < 8; ++k8)
        w[c * 8 + k8] = *(const short8*)(wrow + k8 * 16 + hi8);
    }
    float bs[2][2][4];
    #pragma unroll
    for (int p = 0; p < 2; ++p) {
      int pi = tid + p * 256, op = (pi & 7) << 1;
      #pragma unroll
      for (int k = 0; k < 2; ++k) {
        int o = op + k;
        #pragma unroll
        for (int g = 0; g < 4; ++g)
          bs[p][k][g] = bih1[g * 1024 + j0 + o] + bhh1[g * 1024 + j0 + o];
      }
    }

    for (int s = 0; s < Tn; ++s) {
      const int t = s;
      const unsigned short* h1rd = h1buf + ((t + 1) & 1) * BHe;
      unsigned short* h1wr = h1buf + (t & 1) * BHe;
      f32x16 acc0 = {}, acc1 = {};

      auto ldc = [&](int cc, int d) {
        if (cc < 2) {
          const char* p = (const char*)(x + ((size_t)r0 * Tn + t) * In + cc * 128 + sg * 8);
          #pragma unroll
          for (int j = 0; j < 4; ++j) GLD16(rs[d][j], p + (size_t)j * (16 * Tn * In * 2));
        } else {
          const char* p = (const char*)(h1rd + (size_t)r0 * Hn + (cc - 2) * 128 + sg * 8);
          #pragma unroll
          for (int j = 0; j < 4; ++j) GLD16C(rs[d][j], p + j * (16 * Hn * 2));
        }
      };
      ldc(0, 0); ldc(1, 1); ldc(2, 2); ldc(3, 3);

      #pragma unroll
      for (int c = 0; c < 10; ++c) {
        unsigned short* buf = (c & 1) ? sbuf1 : sbuf0;
        STAGE_WAIT(9 - c);
        {
          unsigned short* db = buf + r0 * SP + sg * 8;
          #pragma unroll
          for (int j = 0; j < 4; ++j) *(uint4*)(db + j * (16 * SP)) = rs[c & 3][j];
        }
        if (c + 4 < 10) ldc(c + 4, c & 3);
        RAW_BARRIER();
        const unsigned short* ab = buf + arow * SP + hi8;
        #pragma unroll
        for (int k8 = 0; k8 < 8; k8 += 2) {
          acc0 = __builtin_amdgcn_mfma_f32_32x32x16_bf16(*(const short8*)(ab + k8 * 16),      w[c * 8 + k8],     acc0, 0, 0, 0);
          acc1 = __builtin_amdgcn_mfma_f32_32x32x16_bf16(*(const short8*)(ab + k8 * 16 + 16), w[c * 8 + k8 + 1], acc1, 0, 0, 0);
        }
      }
      // one more raw barrier so last ds_reads complete before sG overwrite ordering below
      RAW_BARRIER();

      f32x16 accv = acc0 + acc1;
      #pragma unroll
      for (int i = 0; i < 16; ++i) {  // C/D: col=lane&31, row=(reg&3)+8*(reg>>2)+4*(lane>>5)
        int rm = (i & 3) + ((i >> 2) << 3) + ((lane >> 5) << 2);
        sG[(mtile * 32 + rm) * 65 + brow] = accv[i];
      }
      __syncthreads();

      #pragma unroll
      for (int p = 0; p < 2; ++p) {
        int pi = tid + p * 256;
        int b = pi >> 3, op = (pi & 7) << 1;
        const float* gb = sG + b * 65;
        unsigned int pack = 0;
        #pragma unroll
        for (int k = 0; k < 2; ++k) {
          int o = op + k, e = b * 16 + o;
          float ig = gb[o]      + bs[p][k][0];
          float fg = gb[16 + o] + bs[p][k][1];
          float gg = gb[32 + o] + bs[p][k][2];
          float og = gb[48 + o] + bs[p][k][3];
          float cn = sigm(fg) * sc[e] + sigm(ig) * tanhf_(gg);
          sc[e] = cn;
          pack |= ((unsigned int)f2b(sigm(og) * tanhf_(cn))) << (16 * k);
        }
        st32a(h1wr + b * Hn + j0 + op, pack);
      }
      grid_barrier(arrive, bid, tid, lane, s + 1);
    }
    grid_barrier(arrive, bid, tid, lane, Tn + 1);

  } else if (bid < NL1 + NL2) {
    // =================== layer 2 ===================
    const int j0 = (bid - NL1) << 3;
    const int mtile = wid & 1, ks = wid >> 1;
    const int arow = mtile * 32 + (lane & 31);
    const int brow = lane & 31;
    const int gr = ((brow >> 3) << 10) + j0 + (brow & 7);
    const int hi8 = (lane >> 5) << 3;

    short8 w[80];
    if (ks == 0) {
      #pragma unroll
      for (int c = 0; c < 10; ++c)
        #pragma unroll
        for (int k8 = 0; k8 < 8; ++k8)
          w[c * 8 + k8] = *(const short8*)(Wih2 + (size_t)gr * 1280 + c * 128 + k8 * 16 + hi8);
    } else {
      #pragma unroll
      for (int c = 0; c < 8; ++c)
        #pragma unroll
        for (int k8 = 0; k8 < 8; ++k8)
          w[c * 8 + k8] = *(const short8*)(Whh2 + (size_t)gr * Hn + c * 128 + k8 * 16 + hi8);
    }
    float bs[2][4];
    {
      int op = (tid & 3) << 1;
      #pragma unroll
      for (int k = 0; k < 2; ++k) {
        int o = op + k;
        #pragma unroll
        for (int g = 0; g < 4; ++g)
          bs[k][g] = bih2[g * 1024 + j0 + o] + bhh2[g * 1024 + j0 + o];
      }
    }

    grid_barrier(arrive, bid, tid, lane, 1);

    for (int s = 1; s <= Tn; ++s) {
      const int t = s - 1;
      const unsigned short* h1rd = h1buf + (t & 1) * BHe;        // h1(t)
      const unsigned short* h2rd = h2buf + ((t + 1) & 1) * BHe;  // h2(t-1)
      unsigned short* h2wr = h2buf + (t & 1) * BHe;              // h2(t)
      f32x16 acc0 = {}, acc1 = {};

      auto ldc = [&](int cc, int d) {
        if (cc < 2) {
          const char* p = (const char*)(x + ((size_t)r0 * Tn + t) * In + cc * 128 + sg * 8);
          #pragma unroll
          for (int j = 0; j < 4; ++j) GLD16(rs[d][j], p + (size_t)j * (16 * Tn * In * 2));
        } else {
          const unsigned short* src = (cc < 10) ? (h1rd + (cc - 2) * 128)
                                                : (h2rd + (cc - 10) * 128);
          const char* p = (const char*)(src + (size_t)r0 * Hn + sg * 8);
          #pragma unroll
          for (int j = 0; j < 4; ++j) GLD16C(rs[d][j], p + j * (16 * Hn * 2));
        }
      };
      ldc(0, 0); ldc(1, 1); ldc(2, 2); ldc(3, 3);

      #pragma unroll
      for (int c = 0; c < 18; ++c) {
        unsigned short* buf = (c & 1) ? sbuf1 : sbuf0;
        STAGE_WAIT(17 - c);
        {
          unsigned short* db = buf + r0 * SP + sg * 8;
          #pragma unroll
          for (int j = 0; j < 4; ++j) *(uint4*)(db + j * (16 * SP)) = rs[c & 3][j];
        }
        if (c + 4 < 18) ldc(c + 4, c & 3);
        RAW_BARRIER();
        bool active = (ks == 0) ? (c < 10) : (c >= 10);
        if (active) {
          int ib = ((ks == 0) ? c : (c - 10)) * 8;
          const unsigned short* ab = buf + arow * SP + hi8;
          #pragma unroll
          for (int k8 = 0; k8 < 8; k8 += 2) {
            acc0 = __builtin_amdgcn_mfma_f32_32x32x16_bf16(*(const short8*)(ab + k8 * 16),      w[ib + k8],     acc0, 0, 0, 0);
            acc1 = __builtin_amdgcn_mfma_f32_32x32x16_bf16(*(const short8*)(ab + k8 * 16 + 16), w[ib + k8 + 1], acc1, 0, 0, 0);
          }
        }
      }
      RAW_BARRIER();

      f32x16 accv = acc0 + acc1;
      #pragma unroll
      for (int i = 0; i < 16; ++i) {
        int rm = (i & 3) + ((i >> 2) << 3) + ((lane >> 5) << 2);
        sG[ks * 2112 + (mtile * 32 + rm) * 33 + brow] = accv[i];
      }
      __syncthreads();

      {
        int b = tid >> 2, op = (tid & 3) << 1;
        const float* g0 = sG + b * 33;
        const float* g1 = sG + 2112 + b * 33;
        unsigned int pack = 0;
        #pragma unroll
        for (int k = 0; k < 2; ++k) {
          int o = op + k, e = b * 8 + o;
          float ig = g0[o]      + g1[o]      + bs[k][0];
          float fg = g0[8 + o]  + g1[8 + o]  + bs[k][1];
          float gg = g0[16 + o] + g1[16 + o] + bs[k][2];
          float og = g0[24 + o] + g1[24 + o] + bs[k][3];
          float cn = sigm(fg) * sc[e] + sigm(ig) * tanhf_(gg);
          sc[e] = cn;
          pack |= ((unsigned int)f2b(sigm(og) * tanhf_(cn))) << (16 * k);
        }
        st32a(h2wr + b * Hn + j0 + op, pack);
      }
      grid_barrier(arrive, bid, tid, lane, s + 1);
    }

  } else {
    // =================== head ===================
    const int o0 = (bid - NL1 - NL2) << 4;
    const int quad = lane >> 4;
    const int l15 = lane & 15;
    const int hi8y = quad << 3;

    short8 wy[40];
    #pragma unroll
    for (int c = 0; c < 10; ++c)
      #pragma unroll
      for (int q = 0; q < 4; ++q)
        wy[c * 4 + q] = *(const short8*)(Wl + (size_t)(o0 + l15) * 1280 + c * 128 + q * 32 + hi8y);
    const float blv = bl[o0 + l15];

    grid_barrier(arrive, bid, tid, lane, 1);
    grid_barrier(arrive, bid, tid, lane, 2);

    for (int s = 2; s <= Tn + 1; ++s) {
      const int t = s - 2;
      const unsigned short* h2rd = h2buf + (t & 1) * BHe;   // h2(t)
      f32x4 acc0 = {}, acc1 = {};

      auto ldc = [&](int cc, int d) {
        if (cc < 2) {
          const char* p = (const char*)(x + ((size_t)r0 * Tn + t) * In + cc * 128 + sg * 8);
          #pragma unroll
          for (int j = 0; j < 4; ++j) GLD16(rs[d][j], p + (size_t)j * (16 * Tn * In * 2));
        } else {
          const char* p = (const char*)(h2rd + (size_t)r0 * Hn + (cc - 2) * 128 + sg * 8);
          #pragma unroll
          for (int j = 0; j < 4; ++j) GLD16C(rs[d][j], p + j * (16 * Hn * 2));
        }
      };
      ldc(0, 0); ldc(1, 1); ldc(2, 2); ldc(3, 3);

      #pragma unroll
      for (int c = 0; c < 10; ++c) {
        unsigned short* buf = (c & 1) ? sbuf1 : sbuf0;
        STAGE_WAIT(9 - c);
        {
          unsigned short* db = buf + r0 * SP + sg * 8;
          #pragma unroll
          for (int j = 0; j < 4; ++j) *(uint4*)(db + j * (16 * SP)) = rs[c & 3][j];
        }
        if (c + 4 < 10) ldc(c + 4, c & 3);
        RAW_BARRIER();
        const unsigned short* ab = buf + (wid * 16 + l15) * SP + hi8y;
        acc0 = __builtin_amdgcn_mfma_f32_16x16x32_bf16(*(const short8*)(ab),      wy[c * 4 + 0], acc0, 0, 0, 0);
        acc1 = __builtin_amdgcn_mfma_f32_16x16x32_bf16(*(const short8*)(ab + 32), wy[c * 4 + 1], acc1, 0, 0, 0);
        acc0 = __builtin_amdgcn_mfma_f32_16x16x32_bf16(*(const short8*)(ab + 64), wy[c * 4 + 2], acc0, 0, 0, 0);
        acc1 = __builtin_amdgcn_mfma_f32_16x16x32_bf16(*(const short8*)(ab + 96), wy[c * 4 + 3], acc1, 0, 0, 0);
      }
      RAW_BARRIER();

      f32x4 accv = acc0 + acc1;
      #pragma unroll
      for (int i = 0; i < 4; ++i) {   // C/D 16x16: col=lane&15, row=(lane>>4)*4+reg
        int b = wid * 16 + quad * 4 + i;
        out[((size_t)b * Tn + t) * On + o0 + l15] = accv[i] + blv;
      }
      if (s <= Tn) grid_barrier(arrive, bid, tid, lane, s + 1);
    }
  }
}

extern "C" void kernel_launch(void* const* d_in, const int* in_sizes, int n_in,
                              void* d_out, int out_size, void* d_ws, size_t ws_size,
                              hipStream_t stream) {
  (void)in_sizes; (void)n_in; (void)out_size; (void)ws_size;
  const float* xf    = (const float*)d_in[0];
  const float* Wih1f = (const float*)d_in[1];
  const float* Whh1f = (const float*)d_in[2];
  const float* bih1  = (const float*)d_in[3];
  const float* bhh1  = (const float*)d_in[4];
  const float* Wih2f = (const float*)d_in[5];
  const float* Whh2f = (const float*)d_in[6];
  const float* bih2  = (const float*)d_in[7];
  const float* bhh2  = (const float*)d_in[8];
  const float* Wlf   = (const float*)d_in[9];
  const float* bl    = (const float*)d_in[10];
  float* out = (float*)d_out;

  char* ws = (char*)d_ws;
  unsigned short* Wih1b = (unsigned short*)(ws + WS_WIH1);
  unsigned short* Whh1b = (unsigned short*)(ws + WS_WHH1);
  unsigned short* Wih2b = (unsigned short*)(ws + WS_WIH2);
  unsigned short* Whh2b = (unsigned short*)(ws + WS_WHH2);
  unsigned short* Wlb   = (unsigned short*)(ws + WS_WL);
  unsigned short* xb    = (unsigned short*)(ws + WS_X);
  unsigned short* h1buf = (unsigned short*)(ws + WS_H1);
  unsigned short* h2buf = (unsigned short*)(ws + WS_H2);
  int* arrive           = (int*)(ws + WS_ARR);

  hipLaunchKernelGGL(cvt_bf16, dim3(1024), dim3(256), 0, stream, Wih1f, Wih1b, 262144);
  hipLaunchKernelGGL(cvt_bf16, dim3(4096), dim3(256), 0, stream, Whh1f, Whh1b, 1048576);
  hipLaunchKernelGGL(cvt_bf16, dim3(5120), dim3(256), 0, stream, Wih2f, Wih2b, 1310720);
  hipLaunchKernelGGL(cvt_bf16, dim3(4096), dim3(256), 0, stream, Whh2f, Whh2b, 1048576);
  hipLaunchKernelGGL(cvt_bf16, dim3(320),  dim3(256), 0, stream, Wlf,   Wlb,   81920);
  hipLaunchKernelGGL(cvt_bf16, dim3(4096), dim3(256), 0, stream, xf,    xb,    1048576);

  hipLaunchKernelGGL(prep_zero, dim3(64), dim3(256), 0, stream, h1buf, h2buf, arrive);

  hipLaunchKernelGGL(lstm_persist, dim3(NBLK), dim3(256), SMEM_SZ, stream,
                     xb, Wih1b, Whh1b, bih1, bhh1, Wih2b, Whh2b, bih2, bhh2, Wlb, bl,
                     out, h1buf, h2buf, arrive);
}

// Round 6
// 2149.720 us; speedup vs baseline: 2.9716x; 1.0925x over previous
//
#include <hip/hip_runtime.h>

// DeepLSTM on MI355X — persistent kernel (plain launch, 208 blocks, co-resident),
// weights persistent in VGPR/AGPR (256-thr blocks = 1 wave/SIMD; 512-thr spills, R10).
// ROUND 8: h relay loads = inline-asm global_load_dwordx4 sc1 + manual vmcnt pipeline.
// ROUND 9: centralized two-phase grid barrier. 3825 -> 2831 us.
// ROUND 11: relay map coalesced to 128B lines (8x fewer MALL requests). 2831 -> 2349 us.
// ROUND 12: MALL is now BANDWIDTH-bound (44 MB/step of sc1 h-reads = 4.8 TB/s). Halve
//   h bytes by batch-split re-tiling (register-safe version of R10's goal): L1 = 64 blk
//   = 2 batch-halves x 32 cols; L2 = 128 blk = 2 x 16 cols. Each block reads h for only
//   32 batch rows -> 23 MB/step. Chunks halve to 8KB (32 rows). Weights: L1 w[80]
//   unchanged, L2 w[72] (ks split 9/9). Head unchanged. Grid stays 208.

typedef __attribute__((ext_vector_type(8))) short short8;
typedef __attribute__((ext_vector_type(16))) float f32x16;
typedef __attribute__((ext_vector_type(4))) float f32x4;

#define Tn 256
#define In 256
#define Hn 1024
#define On 256
#define SP 136            // LDS act row stride (elems): 272B rows, 16B-aligned
#define NL1 64
#define NL2 128
#define NY  16
#define NBLK (NL1 + NL2 + NY)   // 208
#define CHUNK_B 17408     // head chunk: 64 rows x SP x 2B. L1/L2 use first 8704 (32 rows)
#define SMEM_SZ 55808     // 2*CHUNK_B + 16896 (gate xchg) + 4096 (cell state)
#define BHe 65536
#define RELEASE_IDX 240   // release flag: own 64B line (arrival flags occupy idx 0..207)

// d_ws layout
#define WS_WIH1 0
#define WS_WHH1 2097152
#define WS_WIH2 10485760
#define WS_WHH2 20971520
#define WS_WL   29360128
#define WS_X    30015488
#define WS_H1   38404096
#define WS_H2   38666240
#define WS_ARR  38928384

// s_waitcnt lgkmcnt(0), vmcnt/expcnt unconstrained (gfx9 encoding)
#define WAIT_LGKM0() __builtin_amdgcn_s_waitcnt(0xC07F)
#define RAW_BARRIER() do { \
    WAIT_LGKM0(); \
    __builtin_amdgcn_sched_barrier(0); \
    __builtin_amdgcn_s_barrier(); \
    __builtin_amdgcn_sched_barrier(0); \
  } while (0)

// Wait for relay loads, 2 loads/chunk (L1/L2): allow `rem` future chunks in flight.
#define STAGE_WAIT2(rem) do { \
    __builtin_amdgcn_sched_barrier(0); \
    if ((rem) >= 3)      asm volatile("s_waitcnt vmcnt(6)" ::: "memory"); \
    else if ((rem) == 2) asm volatile("s_waitcnt vmcnt(4)" ::: "memory"); \
    else if ((rem) == 1) asm volatile("s_waitcnt vmcnt(2)" ::: "memory"); \
    else                 asm volatile("s_waitcnt vmcnt(0)" ::: "memory"); \
    __builtin_amdgcn_sched_barrier(0); \
  } while (0)

// Wait for relay loads, 4 loads/chunk (head).
#define STAGE_WAIT4(rem) do { \
    __builtin_amdgcn_sched_barrier(0); \
    if ((rem) >= 3)      asm volatile("s_waitcnt vmcnt(12)" ::: "memory"); \
    else if ((rem) == 2) asm volatile("s_waitcnt vmcnt(8)"  ::: "memory"); \
    else if ((rem) == 1) asm volatile("s_waitcnt vmcnt(4)"  ::: "memory"); \
    else                 asm volatile("s_waitcnt vmcnt(0)"  ::: "memory"); \
    __builtin_amdgcn_sched_barrier(0); \
  } while (0)

// Plain cached 16B load (x: immutable, L1/L2-cacheable)
#define GLD16(dst, ptr) \
  asm volatile("global_load_dwordx4 %0, %1, off" : "=v"(dst) : "v"(ptr))
// Agent-coherent 16B load (h: sc1 -> coherence point, TA-coalescable)
#define GLD16C(dst, ptr) \
  asm volatile("global_load_dwordx4 %0, %1, off sc1" : "=v"(dst) : "v"(ptr))

static __device__ __forceinline__ unsigned short f2b(float f) {
  union { float f; unsigned int i; } v; v.f = f;
  unsigned int u = v.i;
  return (unsigned short)((u + 0x7FFFu + ((u >> 16) & 1u)) >> 16);  // RNE
}
static __device__ __forceinline__ float sigm(float x) { return 1.0f / (1.0f + __expf(-x)); }
static __device__ __forceinline__ float tanhf_(float x) {
  float ax = fabsf(x);
  float e = __expf(-2.0f * ax);
  return copysignf((1.0f - e) / (1.0f + e), x);
}
static __device__ __forceinline__ int ld32a(const void* p) {
  return __hip_atomic_load((const int*)p, __ATOMIC_RELAXED, __HIP_MEMORY_SCOPE_AGENT);
}
static __device__ __forceinline__ void st32a(void* p, unsigned int v) {
  __hip_atomic_store((unsigned int*)p, v, __ATOMIC_RELAXED, __HIP_MEMORY_SCOPE_AGENT);
}
static __device__ __forceinline__ void st64a(void* p, unsigned long long v) {
  __hip_atomic_store((unsigned long long*)p, v, __ATOMIC_RELAXED, __HIP_MEMORY_SCOPE_AGENT);
}

static __device__ __forceinline__ void grid_barrier(int* arrive, int bid, int tid,
                                                    int lane, int tgt) {
  __syncthreads();   // full drain (vmcnt0): h-stores visible before publish
  if (tid == 0)
    st32a(&arrive[bid], (unsigned int)tgt);
  if (bid == 0) {
    // master: wave 0 sweeps all arrival flags, then publishes release
    if (tid < 64) {
      bool done = false;
      while (!done) {
        bool ok = true;
        #pragma unroll
        for (int j = 0; j < 4; ++j) {
          int idx = lane + j * 64;
          if (idx < NBLK) {
            int v = ld32a(&arrive[idx]);
            ok = ok && (v >= tgt);
          }
        }
        done = __all(ok);
        if (!done) __builtin_amdgcn_s_sleep(1);
      }
      if (tid == 0)
        st32a(&arrive[RELEASE_IDX], (unsigned int)tgt);
    }
    __syncthreads();
  } else {
    // followers: one lane polls the single release line
    if (tid == 0) {
      while (ld32a(&arrive[RELEASE_IDX]) < tgt) __builtin_amdgcn_s_sleep(1);
    }
    __syncthreads();
  }
}

__global__ void __launch_bounds__(256) cvt_bf16(const float* __restrict__ src,
                                                unsigned short* __restrict__ dst, int n4) {
  int i = blockIdx.x * blockDim.x + threadIdx.x;
  if (i >= n4) return;
  float4 v = ((const float4*)src)[i];
  ushort4 o;
  o.x = f2b(v.x); o.y = f2b(v.y); o.z = f2b(v.z); o.w = f2b(v.w);
  ((ushort4*)dst)[i] = o;
}

__global__ void __launch_bounds__(256) prep_zero(unsigned short* h1buf,
                                                 unsigned short* h2buf,
                                                 int* arrive) {
  int i = blockIdx.x * blockDim.x + threadIdx.x;
  st64a((unsigned long long*)h1buf + i, 0ull);
  st64a((unsigned long long*)h1buf + 16384 + i, 0ull);
  st64a((unsigned long long*)h2buf + i, 0ull);
  st64a((unsigned long long*)h2buf + 16384 + i, 0ull);
  if (i < 256) st32a(arrive + i, 0u);
}

__global__ void __launch_bounds__(256, 1) lstm_persist(
    const unsigned short* __restrict__ x,
    const unsigned short* __restrict__ Wih1, const unsigned short* __restrict__ Whh1,
    const float* __restrict__ bih1, const float* __restrict__ bhh1,
    const unsigned short* __restrict__ Wih2, const unsigned short* __restrict__ Whh2,
    const float* __restrict__ bih2, const float* __restrict__ bhh2,
    const unsigned short* __restrict__ Wl,  const float* __restrict__ bl,
    float* __restrict__ out,
    unsigned short* __restrict__ h1buf, unsigned short* __restrict__ h2buf,
    int* __restrict__ arrive)
{
  extern __shared__ char smem[];
  unsigned short* sbuf0 = (unsigned short*)smem;
  unsigned short* sbuf1 = (unsigned short*)(smem + CHUNK_B);
  float* sG = (float*)(smem + 2 * CHUNK_B);
  float* sc = (float*)(smem + 2 * CHUNK_B + 16896);

  const int tid = threadIdx.x;
  const int bid = blockIdx.x;
  const int lane = tid & 63;
  const int wid = tid >> 6;
  const int r0  = tid >> 4;           // base staging row 0..15
  const int sg  = tid & 15;           // 16B column slot within 256B row-chunk
  const int l31 = lane & 31;
  const int hi8 = (lane >> 5) << 3;

  for (int e = tid; e < 1024; e += 256) sc[e] = 0.0f;

  if (bid < NL1) {
    // ========= layer 1: 64 blocks = 2 batch-halves x 32 h-cols (32 batch rows) =========
    const int bh = bid & 1;
    const int rb = bh << 5;                    // batch row base
    const int j0 = (bid >> 1) << 5;            // 32 h-cols
    const int gr = wid * 1024 + j0 + l31;      // gate row (wave wid = gate wid)

    uint4 rs[4][2];                            // depth-4 relay: 32B/thread/chunk

    short8 w[80];
    #pragma unroll
    for (int c = 0; c < 10; ++c) {
      const unsigned short* wrow = (c < 2) ? (Wih1 + (size_t)gr * In + c * 128)
                                           : (Whh1 + (size_t)gr * Hn + (c - 2) * 128);
      #pragma unroll
      for (int k8 = 0; k8 < 8; ++k8)
        w[c * 8 + k8] = *(const short8*)(wrow + k8 * 16 + hi8);
    }
    float bs[4][4];
    {
      int op4 = (tid & 7) << 2;
      #pragma unroll
      for (int k = 0; k < 4; ++k) {
        int o = op4 + k;
        #pragma unroll
        for (int g = 0; g < 4; ++g)
          bs[k][g] = bih1[g * 1024 + j0 + o] + bhh1[g * 1024 + j0 + o];
      }
    }

    for (int s = 0; s < Tn; ++s) {
      const int t = s;
      const unsigned short* h1rd = h1buf + ((t + 1) & 1) * BHe;
      unsigned short* h1wr = h1buf + (t & 1) * BHe;
      f32x16 acc0 = {}, acc1 = {};

      auto ldc = [&](int cc, int d) {
        if (cc < 2) {
          const char* p = (const char*)(x + ((size_t)(rb + r0) * Tn + t) * In + cc * 128 + sg * 8);
          GLD16(rs[d][0], p);
          GLD16(rs[d][1], p + 16 * Tn * In * 2);
        } else {
          const char* p = (const char*)(h1rd + (size_t)(rb + r0) * Hn + (cc - 2) * 128 + sg * 8);
          GLD16C(rs[d][0], p);
          GLD16C(rs[d][1], p + 16 * Hn * 2);
        }
      };
      ldc(0, 0); ldc(1, 1); ldc(2, 2); ldc(3, 3);

      #pragma unroll
      for (int c = 0; c < 10; ++c) {
        unsigned short* buf = (c & 1) ? sbuf1 : sbuf0;
        STAGE_WAIT2(9 - c);
        {
          unsigned short* db = buf + r0 * SP + sg * 8;
          *(uint4*)db = rs[c & 3][0];
          *(uint4*)(db + 16 * SP) = rs[c & 3][1];
        }
        if (c + 4 < 10) ldc(c + 4, c & 3);
        RAW_BARRIER();
        const unsigned short* ab = buf + l31 * SP + hi8;
        #pragma unroll
        for (int k8 = 0; k8 < 8; k8 += 2) {
          acc0 = __builtin_amdgcn_mfma_f32_32x32x16_bf16(*(const short8*)(ab + k8 * 16),      w[c * 8 + k8],     acc0, 0, 0, 0);
          acc1 = __builtin_amdgcn_mfma_f32_32x32x16_bf16(*(const short8*)(ab + k8 * 16 + 16), w[c * 8 + k8 + 1], acc1, 0, 0, 0);
        }
      }
      RAW_BARRIER();

      f32x16 accv = acc0 + acc1;
      #pragma unroll
      for (int i = 0; i < 16; ++i) {  // C/D: col=lane&31 (gate col), row=batch rm
        int rm = (i & 3) + ((i >> 2) << 3) + ((lane >> 5) << 2);
        sG[wid * 1056 + rm * 33 + l31] = accv[i];
      }
      __syncthreads();

      {
        int b = tid >> 3, op4 = (tid & 7) << 2;
        unsigned int pk0 = 0, pk1 = 0;
        #pragma unroll
        for (int k = 0; k < 4; ++k) {
          int o = op4 + k, e = b * 32 + o;
          float ig = sG[       b * 33 + o] + bs[k][0];
          float fg = sG[1056 + b * 33 + o] + bs[k][1];
          float gg = sG[2112 + b * 33 + o] + bs[k][2];
          float og = sG[3168 + b * 33 + o] + bs[k][3];
          float cn = sigm(fg) * sc[e] + sigm(ig) * tanhf_(gg);
          sc[e] = cn;
          unsigned int hb = f2b(sigm(og) * tanhf_(cn));
          if (k < 2) pk0 |= hb << (16 * k); else pk1 |= hb << (16 * (k - 2));
        }
        st64a(h1wr + (size_t)(rb + b) * Hn + j0 + op4,
              ((unsigned long long)pk1 << 32) | pk0);
      }
      grid_barrier(arrive, bid, tid, lane, s + 1);
    }
    grid_barrier(arrive, bid, tid, lane, Tn + 1);

  } else if (bid < NL1 + NL2) {
    // ========= layer 2: 128 blocks = 2 batch-halves x 16 h-cols (32 batch rows) =========
    const int lb = bid - NL1;
    const int bh = lb & 1;
    const int rb = bh << 5;
    const int j0 = (lb >> 1) << 4;             // 16 h-cols
    const int ntile = wid & 1, ks = wid >> 1;
    const int grow = ntile * 32 + l31;         // gate row within block 0..63
    const int gr = ((grow >> 4) << 10) + j0 + (grow & 15);

    uint4 rs[4][2];

    short8 w[72];                              // K split 9/9 chunks
    if (ks == 0) {
      #pragma unroll
      for (int c = 0; c < 9; ++c)
        #pragma unroll
        for (int k8 = 0; k8 < 8; ++k8)
          w[c * 8 + k8] = *(const short8*)(Wih2 + (size_t)gr * 1280 + c * 128 + k8 * 16 + hi8);
    } else {
      #pragma unroll
      for (int c = 0; c < 9; ++c) {
        const unsigned short* wrow = (c == 0) ? (Wih2 + (size_t)gr * 1280 + 1152)
                                              : (Whh2 + (size_t)gr * Hn + (c - 1) * 128);
        #pragma unroll
        for (int k8 = 0; k8 < 8; ++k8)
          w[c * 8 + k8] = *(const short8*)(wrow + k8 * 16 + hi8);
      }
    }
    float bs[2][4];
    {
      int op2 = (tid & 7) << 1;
      #pragma unroll
      for (int k = 0; k < 2; ++k) {
        int o = op2 + k;
        #pragma unroll
        for (int g = 0; g < 4; ++g)
          bs[k][g] = bih2[g * 1024 + j0 + o] + bhh2[g * 1024 + j0 + o];
      }
    }

    grid_barrier(arrive, bid, tid, lane, 1);

    for (int s = 1; s <= Tn; ++s) {
      const int t = s - 1;
      const unsigned short* h1rd = h1buf + (t & 1) * BHe;        // h1(t)
      const unsigned short* h2rd = h2buf + ((t + 1) & 1) * BHe;  // h2(t-1)
      unsigned short* h2wr = h2buf + (t & 1) * BHe;              // h2(t)
      f32x16 acc0 = {}, acc1 = {};

      auto ldc = [&](int cc, int d) {
        if (cc < 2) {
          const char* p = (const char*)(x + ((size_t)(rb + r0) * Tn + t) * In + cc * 128 + sg * 8);
          GLD16(rs[d][0], p);
          GLD16(rs[d][1], p + 16 * Tn * In * 2);
        } else {
          const unsigned short* src = (cc < 10) ? (h1rd + (cc - 2) * 128)
                                                : (h2rd + (cc - 10) * 128);
          const char* p = (const char*)(src + (size_t)(rb + r0) * Hn + sg * 8);
          GLD16C(rs[d][0], p);
          GLD16C(rs[d][1], p + 16 * Hn * 2);
        }
      };
      ldc(0, 0); ldc(1, 1); ldc(2, 2); ldc(3, 3);

      #pragma unroll
      for (int c = 0; c < 18; ++c) {
        unsigned short* buf = (c & 1) ? sbuf1 : sbuf0;
        STAGE_WAIT2(17 - c);
        {
          unsigned short* db = buf + r0 * SP + sg * 8;
          *(uint4*)db = rs[c & 3][0];
          *(uint4*)(db + 16 * SP) = rs[c & 3][1];
        }
        if (c + 4 < 18) ldc(c + 4, c & 3);
        RAW_BARRIER();
        bool active = (ks == 0) ? (c < 9) : (c >= 9);
        if (active) {
          int ib = ((ks == 0) ? c : (c - 9)) * 8;
          const unsigned short* ab = buf + l31 * SP + hi8;
          #pragma unroll
          for (int k8 = 0; k8 < 8; k8 += 2) {
            acc0 = __builtin_amdgcn_mfma_f32_32x32x16_bf16(*(const short8*)(ab + k8 * 16),      w[ib + k8],     acc0, 0, 0, 0);
            acc1 = __builtin_amdgcn_mfma_f32_32x32x16_bf16(*(const short8*)(ab + k8 * 16 + 16), w[ib + k8 + 1], acc1, 0, 0, 0);
          }
        }
      }
      RAW_BARRIER();

      f32x16 accv = acc0 + acc1;
      #pragma unroll
      for (int i = 0; i < 16; ++i) {
        int rm = (i & 3) + ((i >> 2) << 3) + ((lane >> 5) << 2);
        sG[ks * 2112 + grow * 33 + rm] = accv[i];
      }
      __syncthreads();

      {
        int b = tid >> 3, op2 = (tid & 7) << 1;
        unsigned int pack = 0;
        #pragma unroll
        for (int k = 0; k < 2; ++k) {
          int o = op2 + k, e = b * 16 + o;
          float ig = sG[(     o) * 33 + b] + sG[2112 + (     o) * 33 + b] + bs[k][0];
          float fg = sG[(16 + o) * 33 + b] + sG[2112 + (16 + o) * 33 + b] + bs[k][1];
          float gg = sG[(32 + o) * 33 + b] + sG[2112 + (32 + o) * 33 + b] + bs[k][2];
          float og = sG[(48 + o) * 33 + b] + sG[2112 + (48 + o) * 33 + b] + bs[k][3];
          float cn = sigm(fg) * sc[e] + sigm(ig) * tanhf_(gg);
          sc[e] = cn;
          pack |= ((unsigned int)f2b(sigm(og) * tanhf_(cn))) << (16 * k);
        }
        st32a(h2wr + (size_t)(rb + b) * Hn + j0 + op2, pack);
      }
      grid_barrier(arrive, bid, tid, lane, s + 1);
    }

  } else {
    // =================== head (unchanged): 16 blocks x 16 out-cols ===================
    const int o0 = (bid - NL1 - NL2) << 4;
    const int quad = lane >> 4;
    const int l15 = lane & 15;
    const int hi8y = quad << 3;

    uint4 rs[4][4];

    short8 wy[40];
    #pragma unroll
    for (int c = 0; c < 10; ++c)
      #pragma unroll
      for (int q = 0; q < 4; ++q)
        wy[c * 4 + q] = *(const short8*)(Wl + (size_t)(o0 + l15) * 1280 + c * 128 + q * 32 + hi8y);
    const float blv = bl[o0 + l15];

    grid_barrier(arrive, bid, tid, lane, 1);
    grid_barrier(arrive, bid, tid, lane, 2);

    for (int s = 2; s <= Tn + 1; ++s) {
      const int t = s - 2;
      const unsigned short* h2rd = h2buf + (t & 1) * BHe;   // h2(t)
      f32x4 acc0 = {}, acc1 = {};

      auto ldc = [&](int cc, int d) {
        if (cc < 2) {
          const char* p = (const char*)(x + ((size_t)r0 * Tn + t) * In + cc * 128 + sg * 8);
          #pragma unroll
          for (int j = 0; j < 4; ++j) GLD16(rs[d][j], p + (size_t)j * (16 * Tn * In * 2));
        } else {
          const char* p = (const char*)(h2rd + (size_t)r0 * Hn + (cc - 2) * 128 + sg * 8);
          #pragma unroll
          for (int j = 0; j < 4; ++j) GLD16C(rs[d][j], p + j * (16 * Hn * 2));
        }
      };
      ldc(0, 0); ldc(1, 1); ldc(2, 2); ldc(3, 3);

      #pragma unroll
      for (int c = 0; c < 10; ++c) {
        unsigned short* buf = (c & 1) ? sbuf1 : sbuf0;
        STAGE_WAIT4(9 - c);
        {
          unsigned short* db = buf + r0 * SP + sg * 8;
          #pragma unroll
          for (int j = 0; j < 4; ++j) *(uint4*)(db + j * (16 * SP)) = rs[c & 3][j];
        }
        if (c + 4 < 10) ldc(c + 4, c & 3);
        RAW_BARRIER();
        const unsigned short* ab = buf + (wid * 16 + l15) * SP + hi8y;
        acc0 = __builtin_amdgcn_mfma_f32_16x16x32_bf16(*(const short8*)(ab),      wy[c * 4 + 0], acc0, 0, 0, 0);
        acc1 = __builtin_amdgcn_mfma_f32_16x16x32_bf16(*(const short8*)(ab + 32), wy[c * 4 + 1], acc1, 0, 0, 0);
        acc0 = __builtin_amdgcn_mfma_f32_16x16x32_bf16(*(const short8*)(ab + 64), wy[c * 4 + 2], acc0, 0, 0, 0);
        acc1 = __builtin_amdgcn_mfma_f32_16x16x32_bf16(*(const short8*)(ab + 96), wy[c * 4 + 3], acc1, 0, 0, 0);
      }
      RAW_BARRIER();

      f32x4 accv = acc0 + acc1;
      #pragma unroll
      for (int i = 0; i < 4; ++i) {   // C/D 16x16: col=lane&15, row=(lane>>4)*4+reg
        int b = wid * 16 + quad * 4 + i;
        out[((size_t)b * Tn + t) * On + o0 + l15] = accv[i] + blv;
      }
      if (s <= Tn) grid_barrier(arrive, bid, tid, lane, s + 1);
    }
  }
}

extern "C" void kernel_launch(void* const* d_in, const int* in_sizes, int n_in,
                              void* d_out, int out_size, void* d_ws, size_t ws_size,
                              hipStream_t stream) {
  (void)in_sizes; (void)n_in; (void)out_size; (void)ws_size;
  const float* xf    = (const float*)d_in[0];
  const float* Wih1f = (const float*)d_in[1];
  const float* Whh1f = (const float*)d_in[2];
  const float* bih1  = (const float*)d_in[3];
  const float* bhh1  = (const float*)d_in[4];
  const float* Wih2f = (const float*)d_in[5];
  const float* Whh2f = (const float*)d_in[6];
  const float* bih2  = (const float*)d_in[7];
  const float* bhh2  = (const float*)d_in[8];
  const float* Wlf   = (const float*)d_in[9];
  const float* bl    = (const float*)d_in[10];
  float* out = (float*)d_out;

  char* ws = (char*)d_ws;
  unsigned short* Wih1b = (unsigned short*)(ws + WS_WIH1);
  unsigned short* Whh1b = (unsigned short*)(ws + WS_WHH1);
  unsigned short* Wih2b = (unsigned short*)(ws + WS_WIH2);
  unsigned short* Whh2b = (unsigned short*)(ws + WS_WHH2);
  unsigned short* Wlb   = (unsigned short*)(ws + WS_WL);
  unsigned short* xb    = (unsigned short*)(ws + WS_X);
  unsigned short* h1buf = (unsigned short*)(ws + WS_H1);
  unsigned short* h2buf = (unsigned short*)(ws + WS_H2);
  int* arrive           = (int*)(ws + WS_ARR);

  hipLaunchKernelGGL(cvt_bf16, dim3(1024), dim3(256), 0, stream, Wih1f, Wih1b, 262144);
  hipLaunchKernelGGL(cvt_bf16, dim3(4096), dim3(256), 0, stream, Whh1f, Whh1b, 1048576);
  hipLaunchKernelGGL(cvt_bf16, dim3(5120), dim3(256), 0, stream, Wih2f, Wih2b, 1310720);
  hipLaunchKernelGGL(cvt_bf16, dim3(4096), dim3(256), 0, stream, Whh2f, Whh2b, 1048576);
  hipLaunchKernelGGL(cvt_bf16, dim3(320),  dim3(256), 0, stream, Wlf,   Wlb,   81920);
  hipLaunchKernelGGL(cvt_bf16, dim3(4096), dim3(256), 0, stream, xf,    xb,    1048576);

  hipLaunchKernelGGL(prep_zero, dim3(64), dim3(256), 0, stream, h1buf, h2buf, arrive);

  hipLaunchKernelGGL(lstm_persist, dim3(NBLK), dim3(256), SMEM_SZ, stream,
                     xb, Wih1b, Whh1b, bih1, bhh1, Wih2b, Whh2b, bih2, bhh2, Wlb, bl,
                     out, h1buf, h2buf, arrive);
}

// Round 7
// 1923.328 us; speedup vs baseline: 3.3214x; 1.1177x over previous
//
#include <hip/hip_runtime.h>

// DeepLSTM on MI355X — persistent kernel (plain launch, 208 blocks, co-resident),
// weights persistent in VGPR/AGPR (256-thr blocks = 1 wave/SIMD).
// ROUND 8: h relay loads = inline-asm global_load_dwordx4 sc1 + manual vmcnt pipeline.
// ROUND 9: centralized two-phase grid barrier. 3825 -> 2831 us.
// ROUND 11: relay map coalesced to 128B lines. 2831 -> 2349 us.
// ROUND 12: batch-split tiling halves h bytes (44->23 MB/step). 2349 -> 2150 us.
//   Only -8.5% => MALL bandwidth NOT dominant; serial latency chain is.
// ROUND 13: latency-chain compression. (a) 256-col chunks: L2 18->9, L1 10->5
//   chunk-barriers/step; K-split exact (ks0=Wih2 1280 = chunks 0-4, ks1=Whh2 1024 =
//   chunks 5-8); relay depth 3. (b) split grid barrier into publish/wait_release:
//   chunk 0 (pure x, prefetched pre-publish) is staged+MFMA'd while waiting for
//   release; only h chunks gate on it. Master moved to last head block (idle).

typedef __attribute__((ext_vector_type(8))) short short8;
typedef __attribute__((ext_vector_type(16))) float f32x16;
typedef __attribute__((ext_vector_type(4))) float f32x4;

#define Tn 256
#define In 256
#define Hn 1024
#define On 256
#define SP 136            // head LDS act row stride (elems), 128-col chunks
#define LSP 264           // L1/L2 LDS act row stride (elems), 256-col chunks
#define NL1 64
#define NL2 128
#define NY  16
#define NBLK (NL1 + NL2 + NY)   // 208
#define MASTER_BID (NBLK - 1)   // an idle-ish head block runs the sweep
#define CHUNK_B 17408     // buffer slot: head 64*SP*2=17408; L1/L2 use 32*LSP*2=16896
#define SMEM_SZ 55808     // 2*CHUNK_B + 16896 (gate xchg) + 4096 (cell state)
#define BHe 65536
#define RELEASE_IDX 240   // release flag: own 64B line (arrival flags occupy idx 0..207)

// d_ws layout
#define WS_WIH1 0
#define WS_WHH1 2097152
#define WS_WIH2 10485760
#define WS_WHH2 20971520
#define WS_WL   29360128
#define WS_X    30015488
#define WS_H1   38404096
#define WS_H2   38666240
#define WS_ARR  38928384

// s_waitcnt lgkmcnt(0), vmcnt/expcnt unconstrained (gfx9 encoding)
#define WAIT_LGKM0() __builtin_amdgcn_s_waitcnt(0xC07F)
#define RAW_BARRIER() do { \
    WAIT_LGKM0(); \
    __builtin_amdgcn_sched_barrier(0); \
    __builtin_amdgcn_s_barrier(); \
    __builtin_amdgcn_sched_barrier(0); \
  } while (0)

#define STWAIT_N(n) do { \
    __builtin_amdgcn_sched_barrier(0); \
    asm volatile("s_waitcnt vmcnt(" n ")" ::: "memory"); \
    __builtin_amdgcn_sched_barrier(0); \
  } while (0)

// head: 4 loads/chunk, depth-4 relay
#define STAGE_WAIT4(rem) do { \
    __builtin_amdgcn_sched_barrier(0); \
    if ((rem) >= 3)      asm volatile("s_waitcnt vmcnt(12)" ::: "memory"); \
    else if ((rem) == 2) asm volatile("s_waitcnt vmcnt(8)"  ::: "memory"); \
    else if ((rem) == 1) asm volatile("s_waitcnt vmcnt(4)"  ::: "memory"); \
    else                 asm volatile("s_waitcnt vmcnt(0)"  ::: "memory"); \
    __builtin_amdgcn_sched_barrier(0); \
  } while (0)

// Plain cached 16B load (x: immutable, L1/L2-cacheable)
#define GLD16(dst, ptr) \
  asm volatile("global_load_dwordx4 %0, %1, off" : "=v"(dst) : "v"(ptr))
// Agent-coherent 16B load (h: sc1 -> coherence point, TA-coalescable)
#define GLD16C(dst, ptr) \
  asm volatile("global_load_dwordx4 %0, %1, off sc1" : "=v"(dst) : "v"(ptr))

static __device__ __forceinline__ unsigned short f2b(float f) {
  union { float f; unsigned int i; } v; v.f = f;
  unsigned int u = v.i;
  return (unsigned short)((u + 0x7FFFu + ((u >> 16) & 1u)) >> 16);  // RNE
}
static __device__ __forceinline__ float sigm(float x) { return 1.0f / (1.0f + __expf(-x)); }
static __device__ __forceinline__ float tanhf_(float x) {
  float ax = fabsf(x);
  float e = __expf(-2.0f * ax);
  return copysignf((1.0f - e) / (1.0f + e), x);
}
static __device__ __forceinline__ int ld32a(const void* p) {
  return __hip_atomic_load((const int*)p, __ATOMIC_RELAXED, __HIP_MEMORY_SCOPE_AGENT);
}
static __device__ __forceinline__ void st32a(void* p, unsigned int v) {
  __hip_atomic_store((unsigned int*)p, v, __ATOMIC_RELAXED, __HIP_MEMORY_SCOPE_AGENT);
}
static __device__ __forceinline__ void st64a(void* p, unsigned long long v) {
  __hip_atomic_store((unsigned long long*)p, v, __ATOMIC_RELAXED, __HIP_MEMORY_SCOPE_AGENT);
}

// publish: full drain (vmcnt0 via syncthreads) then arrival store
static __device__ __forceinline__ void publish_arrive(int* arrive, int bid, int tid, int tgt) {
  __syncthreads();
  if (tid == 0)
    st32a(&arrive[bid], (unsigned int)tgt);
}
// wait: master (last head block) sweeps + stores release; followers poll one line
static __device__ __forceinline__ void wait_release(int* arrive, int bid, int tid,
                                                    int lane, int tgt) {
  if (bid == MASTER_BID) {
    if (tid < 64) {
      bool done = false;
      while (!done) {
        bool ok = true;
        #pragma unroll
        for (int j = 0; j < 4; ++j) {
          int idx = lane + j * 64;
          if (idx < NBLK) {
            int v = ld32a(&arrive[idx]);
            ok = ok && (v >= tgt);
          }
        }
        done = __all(ok);
        if (!done) __builtin_amdgcn_s_sleep(1);
      }
      if (tid == 0)
        st32a(&arrive[RELEASE_IDX], (unsigned int)tgt);
    }
  } else {
    if (tid == 0) {
      while (ld32a(&arrive[RELEASE_IDX]) < tgt) __builtin_amdgcn_s_sleep(1);
    }
  }
  __syncthreads();
}

__global__ void __launch_bounds__(256) cvt_bf16(const float* __restrict__ src,
                                                unsigned short* __restrict__ dst, int n4) {
  int i = blockIdx.x * blockDim.x + threadIdx.x;
  if (i >= n4) return;
  float4 v = ((const float4*)src)[i];
  ushort4 o;
  o.x = f2b(v.x); o.y = f2b(v.y); o.z = f2b(v.z); o.w = f2b(v.w);
  ((ushort4*)dst)[i] = o;
}

__global__ void __launch_bounds__(256) prep_zero(unsigned short* h1buf,
                                                 unsigned short* h2buf,
                                                 int* arrive) {
  int i = blockIdx.x * blockDim.x + threadIdx.x;
  st64a((unsigned long long*)h1buf + i, 0ull);
  st64a((unsigned long long*)h1buf + 16384 + i, 0ull);
  st64a((unsigned long long*)h2buf + i, 0ull);
  st64a((unsigned long long*)h2buf + 16384 + i, 0ull);
  if (i < 256) st32a(arrive + i, 0u);
}

__global__ void __launch_bounds__(256, 1) lstm_persist(
    const unsigned short* __restrict__ x,
    const unsigned short* __restrict__ Wih1, const unsigned short* __restrict__ Whh1,
    const float* __restrict__ bih1, const float* __restrict__ bhh1,
    const unsigned short* __restrict__ Wih2, const unsigned short* __restrict__ Whh2,
    const float* __restrict__ bih2, const float* __restrict__ bhh2,
    const unsigned short* __restrict__ Wl,  const float* __restrict__ bl,
    float* __restrict__ out,
    unsigned short* __restrict__ h1buf, unsigned short* __restrict__ h2buf,
    int* __restrict__ arrive)
{
  extern __shared__ char smem[];
  unsigned short* sbuf0 = (unsigned short*)smem;
  unsigned short* sbuf1 = (unsigned short*)(smem + CHUNK_B);
  float* sG = (float*)(smem + 2 * CHUNK_B);
  float* sc = (float*)(smem + 2 * CHUNK_B + 16896);

  const int tid = threadIdx.x;
  const int bid = blockIdx.x;
  const int lane = tid & 63;
  const int wid = tid >> 6;
  const int l31 = lane & 31;
  const int hi8 = (lane >> 5) << 3;
  const int rbase = tid >> 5;         // L1/L2 staging: base row 0..7 (rows rbase+8j)
  const int sl = tid & 31;            // L1/L2 staging: 16B slot within 512B row
  const int r0h = tid >> 4;           // head staging rows
  const int sgh = tid & 15;           // head staging slot

  for (int e = tid; e < 1024; e += 256) sc[e] = 0.0f;

  if (bid < NL1) {
    // ===== layer 1: 64 blk = 2 batch-halves x 32 h-cols; 5 chunks (1x + 4h1) =====
    const int bh = bid & 1;
    const int rb = bh << 5;
    const int j0 = (bid >> 1) << 5;
    const int gr = wid * 1024 + j0 + l31;

    uint4 rs[3][4];                   // depth-3 relay, 64B/thread/chunk

    short8 w[80];                     // subchunks: 0-1 = Wih1, 2-9 = Whh1
    #pragma unroll
    for (int c = 0; c < 10; ++c) {
      const unsigned short* wrow = (c < 2) ? (Wih1 + (size_t)gr * In + c * 128)
                                           : (Whh1 + (size_t)gr * Hn + (c - 2) * 128);
      #pragma unroll
      for (int k8 = 0; k8 < 8; ++k8)
        w[c * 8 + k8] = *(const short8*)(wrow + k8 * 16 + hi8);
    }
    float bs[4][4];
    {
      int op4 = (tid & 7) << 2;
      #pragma unroll
      for (int k = 0; k < 4; ++k) {
        int o = op4 + k;
        #pragma unroll
        for (int g = 0; g < 4; ++g)
          bs[k][g] = bih1[g * 1024 + j0 + o] + bhh1[g * 1024 + j0 + o];
      }
    }

    auto ld_x = [&](int t, int d) {
      const char* p = (const char*)(x + ((size_t)(rb + rbase) * Tn + t) * In) + sl * 16;
      #pragma unroll
      for (int j = 0; j < 4; ++j) GLD16(rs[d][j], p + (size_t)j * (8 * Tn * In * 2));
    };

    ld_x(0, 0);

    for (int s = 0; s < Tn; ++s) {
      const int t = s;
      const unsigned short* h1rd = h1buf + ((t + 1) & 1) * BHe;
      unsigned short* h1wr = h1buf + (t & 1) * BHe;
      f32x16 acc0 = {}, acc1 = {};

      auto ld_h1 = [&](int cc, int d) {   // cc 1..4
        const char* p = (const char*)(h1rd + (size_t)(rb + rbase) * Hn + (cc - 1) * 256) + sl * 16;
        #pragma unroll
        for (int j = 0; j < 4; ++j) GLD16C(rs[d][j], p + j * (8 * Hn * 2));
      };
      auto stage = [&](unsigned short* buf, int d) {
        unsigned short* db = buf + rbase * LSP + sl * 8;
        #pragma unroll
        for (int j = 0; j < 4; ++j) *(uint4*)(db + j * (8 * LSP)) = rs[d][j];
      };
      auto mfmaC = [&](const unsigned short* buf, int sc2) {   // sc2 = 2*chunk
        #pragma unroll
        for (int h = 0; h < 2; ++h) {
          const unsigned short* ab = buf + l31 * LSP + h * 128 + hi8;
          const int ib = (sc2 + h) * 8;
          #pragma unroll
          for (int k8 = 0; k8 < 8; k8 += 2) {
            acc0 = __builtin_amdgcn_mfma_f32_32x32x16_bf16(*(const short8*)(ab + k8 * 16),      w[ib + k8],     acc0, 0, 0, 0);
            acc1 = __builtin_amdgcn_mfma_f32_32x32x16_bf16(*(const short8*)(ab + k8 * 16 + 16), w[ib + k8 + 1], acc1, 0, 0, 0);
          }
        }
      };

      // chunk 0 (x) overlaps release wait
      STWAIT_N("0");
      stage(sbuf0, 0);
      RAW_BARRIER();
      mfmaC(sbuf0, 0);

      wait_release(arrive, bid, tid, lane, s);   // trivial at s=0

      ld_h1(1, 1); ld_h1(2, 2); ld_h1(3, 0);

      #pragma unroll
      for (int c = 1; c <= 4; ++c) {
        unsigned short* buf = (c & 1) ? sbuf1 : sbuf0;
        if (c <= 2)      STWAIT_N("8");
        else if (c == 3) STWAIT_N("4");
        else             STWAIT_N("0");
        stage(buf, c % 3);
        if (c + 3 <= 4) ld_h1(c + 3, (c + 3) % 3);
        RAW_BARRIER();
        mfmaC(buf, 2 * c);
      }
      RAW_BARRIER();

      f32x16 accv = acc0 + acc1;
      #pragma unroll
      for (int i = 0; i < 16; ++i) {  // C/D: col=lane&31, row=(reg&3)+8*(reg>>2)+4*(lane>>5)
        int rm = (i & 3) + ((i >> 2) << 3) + ((lane >> 5) << 2);
        sG[wid * 1056 + rm * 33 + l31] = accv[i];
      }
      __syncthreads();

      if (s + 1 < Tn) ld_x(s + 1, 0);   // next-step x prefetch (drained at publish)

      {
        int b = tid >> 3, op4 = (tid & 7) << 2;
        unsigned int pk0 = 0, pk1 = 0;
        #pragma unroll
        for (int k = 0; k < 4; ++k) {
          int o = op4 + k, e = b * 32 + o;
          float ig = sG[       b * 33 + o] + bs[k][0];
          float fg = sG[1056 + b * 33 + o] + bs[k][1];
          float gg = sG[2112 + b * 33 + o] + bs[k][2];
          float og = sG[3168 + b * 33 + o] + bs[k][3];
          float cn = sigm(fg) * sc[e] + sigm(ig) * tanhf_(gg);
          sc[e] = cn;
          unsigned int hb = f2b(sigm(og) * tanhf_(cn));
          if (k < 2) pk0 |= hb << (16 * k); else pk1 |= hb << (16 * (k - 2));
        }
        st64a(h1wr + (size_t)(rb + b) * Hn + j0 + op4,
              ((unsigned long long)pk1 << 32) | pk0);
      }
      publish_arrive(arrive, bid, tid, s + 1);
    }
    publish_arrive(arrive, bid, tid, Tn + 1);

  } else if (bid < NL1 + NL2) {
    // ===== layer 2: 128 blk = 2 batch-halves x 16 h-cols; 9 chunks (1x+4h1+4h2) =====
    const int lb = bid - NL1;
    const int bh = lb & 1;
    const int rb = bh << 5;
    const int j0 = (lb >> 1) << 4;
    const int ntile = wid & 1, ks = wid >> 1;
    const int grow = ntile * 32 + l31;         // gate row within block 0..63
    const int gr = ((grow >> 4) << 10) + j0 + (grow & 15);

    uint4 rs[3][4];

    short8 w[80];                     // ks0: 10 subchunks Wih2 (K=1280); ks1: 8 Whh2
    if (ks == 0) {
      #pragma unroll
      for (int c = 0; c < 10; ++c)
        #pragma unroll
        for (int k8 = 0; k8 < 8; ++k8)
          w[c * 8 + k8] = *(const short8*)(Wih2 + (size_t)gr * 1280 + c * 128 + k8 * 16 + hi8);
    } else {
      #pragma unroll
      for (int c = 0; c < 8; ++c)
        #pragma unroll
        for (int k8 = 0; k8 < 8; ++k8)
          w[c * 8 + k8] = *(const short8*)(Whh2 + (size_t)gr * Hn + c * 128 + k8 * 16 + hi8);
    }
    float bs[2][4];
    {
      int op2 = (tid & 7) << 1;
      #pragma unroll
      for (int k = 0; k < 2; ++k) {
        int o = op2 + k;
        #pragma unroll
        for (int g = 0; g < 4; ++g)
          bs[k][g] = bih2[g * 1024 + j0 + o] + bhh2[g * 1024 + j0 + o];
      }
    }

    auto ld_x2 = [&](int t, int d) {
      const char* p = (const char*)(x + ((size_t)(rb + rbase) * Tn + t) * In) + sl * 16;
      #pragma unroll
      for (int j = 0; j < 4; ++j) GLD16(rs[d][j], p + (size_t)j * (8 * Tn * In * 2));
    };

    ld_x2(0, 0);
    publish_arrive(arrive, bid, tid, 1);

    for (int s = 1; s <= Tn; ++s) {
      const int t = s - 1;
      const unsigned short* h1rd = h1buf + (t & 1) * BHe;        // h1(t)
      const unsigned short* h2rd = h2buf + ((t + 1) & 1) * BHe;  // h2(t-1)
      unsigned short* h2wr = h2buf + (t & 1) * BHe;              // h2(t)
      f32x16 acc0 = {}, acc1 = {};

      auto ld_hc = [&](int cc, int d) {  // cc 1..4 -> h1, 5..8 -> h2
        const unsigned short* src = (cc < 5) ? (h1rd + (cc - 1) * 256)
                                             : (h2rd + (cc - 5) * 256);
        const char* p = (const char*)(src + (size_t)(rb + rbase) * Hn) + sl * 16;
        #pragma unroll
        for (int j = 0; j < 4; ++j) GLD16C(rs[d][j], p + j * (8 * Hn * 2));
      };
      auto stage = [&](unsigned short* buf, int d) {
        unsigned short* db = buf + rbase * LSP + sl * 8;
        #pragma unroll
        for (int j = 0; j < 4; ++j) *(uint4*)(db + j * (8 * LSP)) = rs[d][j];
      };
      auto mfmaC2 = [&](const unsigned short* buf, int c) {
        bool active = (ks == 0) ? (c < 5) : (c >= 5);
        if (!active) return;
        const int sc2 = (ks == 0) ? (2 * c) : (2 * (c - 5));
        #pragma unroll
        for (int h = 0; h < 2; ++h) {
          const unsigned short* ab = buf + l31 * LSP + h * 128 + hi8;
          const int ib = (sc2 + h) * 8;
          #pragma unroll
          for (int k8 = 0; k8 < 8; k8 += 2) {
            acc0 = __builtin_amdgcn_mfma_f32_32x32x16_bf16(*(const short8*)(ab + k8 * 16),      w[ib + k8],     acc0, 0, 0, 0);
            acc1 = __builtin_amdgcn_mfma_f32_32x32x16_bf16(*(const short8*)(ab + k8 * 16 + 16), w[ib + k8 + 1], acc1, 0, 0, 0);
          }
        }
      };

      STWAIT_N("0");
      stage(sbuf0, 0);
      RAW_BARRIER();
      mfmaC2(sbuf0, 0);

      wait_release(arrive, bid, tid, lane, s);

      ld_hc(1, 1); ld_hc(2, 2); ld_hc(3, 0);

      #pragma unroll
      for (int c = 1; c <= 8; ++c) {
        unsigned short* buf = (c & 1) ? sbuf1 : sbuf0;
        if (c <= 6)      STWAIT_N("8");
        else if (c == 7) STWAIT_N("4");
        else             STWAIT_N("0");
        stage(buf, c % 3);
        if (c + 3 <= 8) ld_hc(c + 3, (c + 3) % 3);
        RAW_BARRIER();
        mfmaC2(buf, c);
      }
      RAW_BARRIER();

      f32x16 accv = acc0 + acc1;
      #pragma unroll
      for (int i = 0; i < 16; ++i) {
        int rm = (i & 3) + ((i >> 2) << 3) + ((lane >> 5) << 2);
        sG[ks * 2112 + grow * 33 + rm] = accv[i];
      }
      __syncthreads();

      if (s < Tn) ld_x2(t + 1, 0);

      {
        int b = tid >> 3, op2 = (tid & 7) << 1;
        unsigned int pack = 0;
        #pragma unroll
        for (int k = 0; k < 2; ++k) {
          int o = op2 + k, e = b * 16 + o;
          float ig = sG[(     o) * 33 + b] + sG[2112 + (     o) * 33 + b] + bs[k][0];
          float fg = sG[(16 + o) * 33 + b] + sG[2112 + (16 + o) * 33 + b] + bs[k][1];
          float gg = sG[(32 + o) * 33 + b] + sG[2112 + (32 + o) * 33 + b] + bs[k][2];
          float og = sG[(48 + o) * 33 + b] + sG[2112 + (48 + o) * 33 + b] + bs[k][3];
          float cn = sigm(fg) * sc[e] + sigm(ig) * tanhf_(gg);
          sc[e] = cn;
          pack |= ((unsigned int)f2b(sigm(og) * tanhf_(cn))) << (16 * k);
        }
        st32a(h2wr + (size_t)(rb + b) * Hn + j0 + op2, pack);
      }
      publish_arrive(arrive, bid, tid, s + 1);
    }

  } else {
    // =================== head: 16 blocks x 16 out-cols (R12 structure) ===============
    const int o0 = (bid - NL1 - NL2) << 4;
    const int quad = lane >> 4;
    const int l15 = lane & 15;
    const int hi8y = quad << 3;

    uint4 rs[4][4];

    short8 wy[40];
    #pragma unroll
    for (int c = 0; c < 10; ++c)
      #pragma unroll
      for (int q = 0; q < 4; ++q)
        wy[c * 4 + q] = *(const short8*)(Wl + (size_t)(o0 + l15) * 1280 + c * 128 + q * 32 + hi8y);
    const float blv = bl[o0 + l15];

    publish_arrive(arrive, bid, tid, 1);
    wait_release(arrive, bid, tid, lane, 1);
    publish_arrive(arrive, bid, tid, 2);
    wait_release(arrive, bid, tid, lane, 2);

    for (int s = 2; s <= Tn + 1; ++s) {
      const int t = s - 2;
      const unsigned short* h2rd = h2buf + (t & 1) * BHe;   // h2(t)
      f32x4 acc0 = {}, acc1 = {};

      auto ldc = [&](int cc, int d) {
        if (cc < 2) {
          const char* p = (const char*)(x + ((size_t)r0h * Tn + t) * In + cc * 128 + sgh * 8);
          #pragma unroll
          for (int j = 0; j < 4; ++j) GLD16(rs[d][j], p + (size_t)j * (16 * Tn * In * 2));
        } else {
          const char* p = (const char*)(h2rd + (size_t)r0h * Hn + (cc - 2) * 128 + sgh * 8);
          #pragma unroll
          for (int j = 0; j < 4; ++j) GLD16C(rs[d][j], p + j * (16 * Hn * 2));
        }
      };
      ldc(0, 0); ldc(1, 1); ldc(2, 2); ldc(3, 3);

      #pragma unroll
      for (int c = 0; c < 10; ++c) {
        unsigned short* buf = (c & 1) ? sbuf1 : sbuf0;
        STAGE_WAIT4(9 - c);
        {
          unsigned short* db = buf + r0h * SP + sgh * 8;
          #pragma unroll
          for (int j = 0; j < 4; ++j) *(uint4*)(db + j * (16 * SP)) = rs[c & 3][j];
        }
        if (c + 4 < 10) ldc(c + 4, c & 3);
        RAW_BARRIER();
        const unsigned short* ab = buf + (wid * 16 + l15) * SP + hi8y;
        acc0 = __builtin_amdgcn_mfma_f32_16x16x32_bf16(*(const short8*)(ab),      wy[c * 4 + 0], acc0, 0, 0, 0);
        acc1 = __builtin_amdgcn_mfma_f32_16x16x32_bf16(*(const short8*)(ab + 32), wy[c * 4 + 1], acc1, 0, 0, 0);
        acc0 = __builtin_amdgcn_mfma_f32_16x16x32_bf16(*(const short8*)(ab + 64), wy[c * 4 + 2], acc0, 0, 0, 0);
        acc1 = __builtin_amdgcn_mfma_f32_16x16x32_bf16(*(const short8*)(ab + 96), wy[c * 4 + 3], acc1, 0, 0, 0);
      }
      RAW_BARRIER();

      f32x4 accv = acc0 + acc1;
      #pragma unroll
      for (int i = 0; i < 4; ++i) {   // C/D 16x16: col=lane&15, row=(lane>>4)*4+reg
        int b = wid * 16 + quad * 4 + i;
        out[((size_t)b * Tn + t) * On + o0 + l15] = accv[i] + blv;
      }
      if (s <= Tn) {
        publish_arrive(arrive, bid, tid, s + 1);
        wait_release(arrive, bid, tid, lane, s + 1);
      }
    }
  }
}

extern "C" void kernel_launch(void* const* d_in, const int* in_sizes, int n_in,
                              void* d_out, int out_size, void* d_ws, size_t ws_size,
                              hipStream_t stream) {
  (void)in_sizes; (void)n_in; (void)out_size; (void)ws_size;
  const float* xf    = (const float*)d_in[0];
  const float* Wih1f = (const float*)d_in[1];
  const float* Whh1f = (const float*)d_in[2];
  const float* bih1  = (const float*)d_in[3];
  const float* bhh1  = (const float*)d_in[4];
  const float* Wih2f = (const float*)d_in[5];
  const float* Whh2f = (const float*)d_in[6];
  const float* bih2  = (const float*)d_in[7];
  const float* bhh2  = (const float*)d_in[8];
  const float* Wlf   = (const float*)d_in[9];
  const float* bl    = (const float*)d_in[10];
  float* out = (float*)d_out;

  char* ws = (char*)d_ws;
  unsigned short* Wih1b = (unsigned short*)(ws + WS_WIH1);
  unsigned short* Whh1b = (unsigned short*)(ws + WS_WHH1);
  unsigned short* Wih2b = (unsigned short*)(ws + WS_WIH2);
  unsigned short* Whh2b = (unsigned short*)(ws + WS_WHH2);
  unsigned short* Wlb   = (unsigned short*)(ws + WS_WL);
  unsigned short* xb    = (unsigned short*)(ws + WS_X);
  unsigned short* h1buf = (unsigned short*)(ws + WS_H1);
  unsigned short* h2buf = (unsigned short*)(ws + WS_H2);
  int* arrive           = (int*)(ws + WS_ARR);

  hipLaunchKernelGGL(cvt_bf16, dim3(1024), dim3(256), 0, stream, Wih1f, Wih1b, 262144);
  hipLaunchKernelGGL(cvt_bf16, dim3(4096), dim3(256), 0, stream, Whh1f, Whh1b, 1048576);
  hipLaunchKernelGGL(cvt_bf16, dim3(5120), dim3(256), 0, stream, Wih2f, Wih2b, 1310720);
  hipLaunchKernelGGL(cvt_bf16, dim3(4096), dim3(256), 0, stream, Whh2f, Whh2b, 1048576);
  hipLaunchKernelGGL(cvt_bf16, dim3(320),  dim3(256), 0, stream, Wlf,   Wlb,   81920);
  hipLaunchKernelGGL(cvt_bf16, dim3(4096), dim3(256), 0, stream, xf,    xb,    1048576);

  hipLaunchKernelGGL(prep_zero, dim3(64), dim3(256), 0, stream, h1buf, h2buf, arrive);

  hipLaunchKernelGGL(lstm_persist, dim3(NBLK), dim3(256), SMEM_SZ, stream,
                     xb, Wih1b, Whh1b, bih1, bhh1, Wih2b, Whh2b, bih2, bhh2, Wlb, bl,
                     out, h1buf, h2buf, arrive);
}